// Round 11
// baseline (350.652 us; speedup 1.0000x reference)
//
#include <hip/hip_runtime.h>
#include <stdint.h>

typedef unsigned short u16;
typedef unsigned int u32;
typedef unsigned long long u64;
using f32x4 = __attribute__((ext_vector_type(4))) float;
using f32x16 = __attribute__((ext_vector_type(16))) float;
using s16x8 = __attribute__((ext_vector_type(8))) short;
using u16x4 = __attribute__((ext_vector_type(4))) unsigned short;
using u32x4 = __attribute__((ext_vector_type(4))) u32;

static constexpr float kQScale = (float)(0.08838834764831845 * 1.4426950408889634);  // SCALE*log2(e)

__device__ __forceinline__ u16 f2bf(float f) {
  uint32_t u = __float_as_uint(f);
  u += 0x7fffu + ((u >> 16) & 1u);   // RNE
  return (u16)(u >> 16);
}

__device__ __forceinline__ float fexp2(float x) {
#if __has_builtin(__builtin_amdgcn_exp2f)
  return __builtin_amdgcn_exp2f(x);
#else
  return exp2f(x);
#endif
}

__device__ __forceinline__ u32 cvtpk(float lo, float hi) {
  u32 r;
  asm("v_cvt_pk_bf16_f32 %0, %1, %2" : "=v"(r) : "v"(lo), "v"(hi));
  return r;
}

// 16x16x32 bf16 MFMA (D=C tied): C/D col=lane&15, row=4*(lane>>4)+reg [m89/m91].
__device__ __forceinline__ void mfma16(f32x4& d, s16x8 a, s16x8 b) {
  asm volatile("v_mfma_f32_16x16x32_bf16 %0, %1, %2, %0" : "+v"(d) : "v"(a), "v"(b));
}
// 32x32x16 bf16 MFMA: A row=lane&31,k=8*(lane>>5)+j; B col=lane&31;
// C/D col=lane&31, row=(reg&3)+8*(reg>>2)+4*(lane>>5) [m74/m101].
__device__ __forceinline__ void mfma32(f32x16& d, s16x8 a, s16x8 b) {
  asm volatile("v_mfma_f32_32x32x16_bf16 %0, %1, %2, %0" : "+v"(d) : "v"(a), "v"(b));
}
__device__ __forceinline__ f32x16 mfma32_z(s16x8 a, s16x8 b) {
  f32x16 d;
  asm volatile("v_mfma_f32_32x32x16_bf16 %0, %1, %2, 0" : "=&v"(d) : "v"(a), "v"(b));
  return d;
}

// async global->LDS, 16B per lane; LDS dest = wave-uniform base + lane*16 (m104).
__device__ __forceinline__ void g2lds16(const void* g, void* l) {
  __builtin_amdgcn_global_load_lds(
      (__attribute__((address_space(1))) void*)(uintptr_t)g,
      (__attribute__((address_space(3))) void*)(uint32_t)(uintptr_t)l, 16, 0, 0);
}

#define BAR() asm volatile("s_barrier" ::: "memory")

// ---------------- fused prep: x->bf16 | weights->bf16 | qkv_w^T | comb bias | mask pack ----
__global__ __launch_bounds__(256) void prep(const float* __restrict__ x, u16* __restrict__ xb,
                                            const float* __restrict__ qw, const float* __restrict__ kw,
                                            const float* __restrict__ vw, const float* __restrict__ ow,
                                            u16* __restrict__ wb4,
                                            const float* __restrict__ qkvw, u16* __restrict__ qkvwT,
                                            const float* __restrict__ qkvb, const float* __restrict__ qb,
                                            const float* __restrict__ kb, const float* __restrict__ vb,
                                            float* __restrict__ cb3,
                                            const int* __restrict__ am, u64* __restrict__ pm) {
  __shared__ u16 tile[32][33];
  const int bid = blockIdx.x, tid = threadIdx.x;
  if (bid < 8192) {                       // x (8192x1024 f32) -> bf16
    int i = (bid * 256 + tid) * 4;
    f32x4 v = *(const f32x4*)(x + i);
    u16x4 o = {f2bf(v.x), f2bf(v.y), f2bf(v.z), f2bf(v.w)};
    *(u16x4*)(xb + i) = o;
  } else if (bid < 12288) {               // 4 weights (1024^2 f32) -> bf16, contiguous
    int idx = bid - 8192;
    int z = idx >> 10;
    const float* in = z == 0 ? qw : z == 1 ? kw : z == 2 ? vw : ow;
    int i = ((idx & 1023) * 256 + tid) * 4;
    f32x4 v = *(const f32x4*)(in + i);
    u16x4 o = {f2bf(v.x), f2bf(v.y), f2bf(v.z), f2bf(v.w)};
    *(u16x4*)(wb4 + (size_t)z * 1048576 + i) = o;
  } else if (bid < 15360) {               // qkv_w (3072x1024) -> qkv_wT (1024x3072) bf16
    int idx = bid - 12288;
    int bx = idx & 31, by = idx >> 5;
    int tx = tid & 31, ty = tid >> 5;
#pragma unroll
    for (int k = 0; k < 4; ++k)
      tile[ty + k * 8][tx] = f2bf(qkvw[(size_t)(by * 32 + ty + k * 8) * 1024 + bx * 32 + tx]);
    __syncthreads();
#pragma unroll
    for (int k = 0; k < 4; ++k)
      qkvwT[(size_t)(bx * 32 + ty + k * 8) * 3072 + by * 32 + tx] = tile[tx][ty + k * 8];
  } else if (bid < 16128) {               // combined bias (fp32 exact); z==0 scaled
    int idx = bid - 15360;
    int z = idx >> 8;
    const float* w = z == 0 ? qw : (z == 1 ? kw : vw);
    const float* ba = z == 0 ? qb : (z == 1 ? kb : vb);
    const float* bi = qkvb + z * 1024;
    int o = (idx & 255) * 4 + (tid >> 6);
    int lane = tid & 63;
    float s = 0.f;
    for (int m = lane; m < 1024; m += 64) s += w[o * 1024 + m] * bi[m];
#pragma unroll
    for (int d = 1; d < 64; d <<= 1) s += __shfl_xor(s, d);
    if (lane == 0) {
      float fin = s + ba[o];
      if (z == 0) fin *= kQScale;
      cb3[z * 1024 + o] = fin;
    }
  } else {                                // mask -> bit-packed KEEP rows (2048 x 32 u64)
    int row = bid - 16128;
    int wv = tid >> 6, lane = tid & 63;
#pragma unroll
    for (int i = 0; i < 8; ++i) {
      int word = wv * 8 + i;
      u64 b = __ballot(am[(size_t)row * 2048 + word * 64 + lane] == 0);
      if (lane == 0) pm[(size_t)row * 32 + word] = b;
    }
  }
}

// ---------------- NT GEMM 128^2 (m97-style) ----------------
template <typename OUT_T, bool BIAS_PER_ROW>
__global__ __launch_bounds__(256, 2) void gemm_nt(const u16* __restrict__ A, int lda, long bsA,
                                                  const u16* __restrict__ B, int ldb, long bsB,
                                                  OUT_T* __restrict__ C, int ldc, long bsC,
                                                  const float* __restrict__ bias, long bsBias,
                                                  int NtilesN, int K, float scale_z0) {
  __shared__ __align__(16) u16 As[128 * 64];
  __shared__ __align__(16) u16 Bs[128 * 64];
  const int z = blockIdx.z;
  const float sc = (z == 0) ? scale_z0 : 1.f;
  A += (size_t)z * bsA; B += (size_t)z * bsB; C += (size_t)z * bsC;
  if (bias) bias += (size_t)z * bsBias;
  const int tm = blockIdx.x / NtilesN, tn = blockIdx.x % NtilesN;
  const int tid = threadIdx.x, lane = tid & 63, w = tid >> 6;
  const int wm = w >> 1, wn = w & 1;
  const int q = lane & 15, g = lane >> 4;
  f32x4 acc[4][4] = {};

  const u16* Ab = A + (size_t)(tm * 128 + (tid >> 3)) * lda + ((tid & 7) << 3);
  const u16* Bb = B + (size_t)(tn * 128 + (tid >> 3)) * ldb + ((tid & 7) << 3);
  char* AsW = (char*)As + (w << 10);
  char* BsW = (char*)Bs + (w << 10);

  for (int k0 = 0; k0 < K; k0 += 64) {
#pragma unroll
    for (int it = 0; it < 4; ++it) {
      g2lds16(Ab + (size_t)(it * 32) * lda + k0, AsW + it * 4096);
      g2lds16(Bb + (size_t)(it * 32) * ldb + k0, BsW + it * 4096);
    }
    __syncthreads();
#pragma unroll
    for (int kk = 0; kk < 2; ++kk) {
      s16x8 af[4], bf[4];
#pragma unroll
      for (int i = 0; i < 4; ++i)
        af[i] = *(const s16x8*)((const char*)As + (wm * 64 + i * 16 + q) * 128 + kk * 64 + g * 16);
#pragma unroll
      for (int i = 0; i < 4; ++i)
        bf[i] = *(const s16x8*)((const char*)Bs + (wn * 64 + i * 16 + q) * 128 + kk * 64 + g * 16);
#pragma unroll
      for (int mf = 0; mf < 4; ++mf)
#pragma unroll
        for (int nf = 0; nf < 4; ++nf) mfma16(acc[mf][nf], af[mf], bf[nf]);
    }
    __syncthreads();
  }
  asm volatile("s_nop 7\n\ts_nop 7");
#pragma unroll
  for (int mf = 0; mf < 4; ++mf)
#pragma unroll
    for (int nf = 0; nf < 4; ++nf) {
      const int row = tm * 128 + wm * 64 + mf * 16 + g * 4;
      const int col = tn * 128 + wn * 64 + nf * 16 + q;
      float bc = (!BIAS_PER_ROW && bias) ? bias[col] : 0.f;
#pragma unroll
      for (int r = 0; r < 4; ++r) {
        float v = acc[mf][nf][r] * sc;
        if (bias) v += BIAS_PER_ROW ? bias[row + r] : bc;
        if constexpr (sizeof(OUT_T) == 2)
          C[(size_t)(row + r) * ldc + col] = (OUT_T)f2bf(v);
        else
          C[(size_t)(row + r) * ldc + col] = (OUT_T)v;
      }
    }
}

// ------- QK projection: 256x128-tile, 8-wave (4Mx2N), m97 flow, 48KB LDS, 2 blocks/CU ----
__global__ __launch_bounds__(512, 4) void gemm_qk(const u16* __restrict__ A,
                                                  const u16* __restrict__ B,
                                                  const float* __restrict__ bias,
                                                  u16* __restrict__ C) {
  __shared__ __align__(16) u16 As[256 * 64];   // 32KB
  __shared__ __align__(16) u16 Bs[128 * 64];   // 16KB
  const int bid = blockIdx.x;
  const int wgid = (bid & 7) * 64 + (bid >> 3);        // XCD-contiguous (512 % 8 == 0)
  const int tm = wgid >> 4, tn = wgid & 15;
  const int tid = threadIdx.x, lane = tid & 63, w = tid >> 6;
  const int wm = w >> 1, wn = w & 1;
  const int q = lane & 15, g = lane >> 4, qk = q & 7;
  f32x4 acc[4][4] = {};

  const int srow = tid >> 3, sch = tid & 7;
  const int gcol = (sch ^ (srow & 7)) << 3;
  const u16* Abase = A + (size_t)(tm * 256 + srow) * 1024 + gcol;
  const u16* Bbase = B + (size_t)(tn * 128 + srow) * 1024 + gcol;
  char* AsW = (char*)As + (w << 10);
  char* BsW = (char*)Bs + (w << 10);

  for (int k0 = 0; k0 < 1024; k0 += 64) {
#pragma unroll
    for (int it = 0; it < 4; ++it)
      g2lds16(Abase + (size_t)(it * 64) * 1024 + k0, AsW + it * 8192);
#pragma unroll
    for (int it = 0; it < 2; ++it)
      g2lds16(Bbase + (size_t)(it * 64) * 1024 + k0, BsW + it * 8192);
    __syncthreads();
#pragma unroll
    for (int kk = 0; kk < 2; ++kk) {
      s16x8 af[4], bf[4];
#pragma unroll
      for (int i = 0; i < 4; ++i)
        af[i] = *(const s16x8*)((const char*)As + (wm * 64 + i * 16 + q) * 128 +
                                ((((kk << 2) + g) ^ qk) << 4));
#pragma unroll
      for (int i = 0; i < 4; ++i)
        bf[i] = *(const s16x8*)((const char*)Bs + (wn * 64 + i * 16 + q) * 128 +
                                ((((kk << 2) + g) ^ qk) << 4));
      __builtin_amdgcn_s_setprio(1);
#pragma unroll
      for (int mf = 0; mf < 4; ++mf)
#pragma unroll
        for (int nf = 0; nf < 4; ++nf) mfma16(acc[mf][nf], af[mf], bf[nf]);
      __builtin_amdgcn_s_setprio(0);
    }
    __syncthreads();
  }
  asm volatile("s_nop 7\n\ts_nop 7");
#pragma unroll
  for (int mf = 0; mf < 4; ++mf) {
    const int row = tm * 256 + wm * 64 + mf * 16 + g * 4;
#pragma unroll
    for (int nf = 0; nf < 4; ++nf) {
      const int col = tn * 128 + wn * 64 + nf * 16 + q;
      const float bc = bias[col];
#pragma unroll
      for (int r = 0; r < 4; ++r)
        C[(size_t)(row + r) * 2048 + col] = f2bf(acc[mf][nf][r] + bc);
    }
  }
}

// ---- flash attention: split-KV (2 streams x 4 waves), KVBLK=32, low-VGPR, exact combine ----
// body(s): stageV(s+2) | qk(s) | BAR | stageK(s+2) (K(s) slot now dead block-wide) |
//          softmax+PV | vmcnt(2) | BAR.
// vmcnt proof (2 loads per stage, FIFO): end body(s) entering = [K(s+1):2,V(s+2):2,K(s+2):2];
// vmcnt(2) lands K(s+1) (read next body) and V(s+2); V(s+1) landed earlier (issued pre-K(s+1)).
__global__ __launch_bounds__(512, 4) void attn_fwd(const u16* __restrict__ Qb, const u16* __restrict__ Kb,
                                                   int ldq, const u16* __restrict__ Vt,
                                                   const u64* __restrict__ pmask,
                                                   u16* __restrict__ Ob) {
  __shared__ __align__(16) char smem[81920];
  // K[t][buf]: smem + (t*2+buf)*8192          [32 kv][256B], chunk XOR (kv&15)
  // V[t][buf]: smem + 32768 + (t*3+buf)*8192  [128 d][64B],  chunk XOR (d&3)
  const int n = blockIdx.x;
  const int slot = n >> 3;
  const int grp = (n & 7) * 4 + (slot >> 4);
  const int qt = slot & 15;
  const int h = grp & 7, b = grp >> 3;
  const int tid = threadIdx.x, w = tid >> 6, lane = tid & 63;
  const int t = w >> 2, ws = w & 3;
  const int ql = lane & 31, hi = lane >> 5;
  const int q0 = qt * 128;
  const int kvbase = b * 2048 + t * 1024;

  s16x8 qf[8];
  const u16* qrow = Qb + (size_t)(b * 2048 + q0 + ws * 32 + ql) * ldq + h * 128 + 8 * hi;
#pragma unroll
  for (int kd = 0; kd < 8; ++kd) qf[kd] = *(const s16x8*)(qrow + 16 * kd);

  f32x16 oacc[4] = {};   // dt: O[q=crow(reg,hi)][d = dt*32+ql]  (stream partial)
  float lp = 0.f;        // per-lane partial row-sum (q=ql, own kv subset)

  const int st = tid & 255;
  const int ksr = st >> 4, ksc = st & 15;  // K staging (32 rows x 16 chunks)
  const int vsr = st >> 2, vsc = st & 3;   // V staging (128 rows x 4 chunks)
  const int sw = ql & 15;
  const u64* pmrow = pmask + (size_t)(q0 + ws * 32 + ql) * 32 + t * 16;

  auto stageK = [&](int buf, int si) {
    const int kv0 = si * 32;
    char* kb = smem + (t * 2 + buf) * 8192 + (ws << 10);
#pragma unroll
    for (int it = 0; it < 2; ++it) {
      int kr = it * 16 + ksr;
      g2lds16(Kb + (size_t)(kvbase + kv0 + kr) * ldq + h * 128 + ((ksc ^ (kr & 15)) << 3),
              kb + it * 4096);
    }
  };
  auto stageV = [&](int buf, int si) {
    const int kv0 = si * 32;
    char* vbp = smem + 32768 + (t * 3 + buf) * 8192 + (ws << 10);
#pragma unroll
    for (int it = 0; it < 2; ++it) {
      int vr = it * 64 + vsr;
      g2lds16(Vt + (size_t)(h * 128 + vr) * 8192 + kvbase + kv0 + ((vsc ^ (vr & 3)) << 3),
              vbp + it * 4096);
    }
  };
  auto qk = [&](f32x16& d0, int kbuf) {
    const char* Kc = smem + (t * 2 + kbuf) * 8192;
#pragma unroll
    for (int kd = 0; kd < 8; ++kd) {
      int c = (2 * kd + hi) ^ sw;
      s16x8 kf = *(const s16x8*)(Kc + ql * 256 + (c << 4));
      if (kd == 0) d0 = mfma32_z(kf, qf[0]);
      else         mfma32(d0, kf, qf[kd]);
    }
  };

  // prologue: V(0),K(0),V(1),K(1); full drain (no in-flight reads possible)
  stageV(0, 0); stageK(0, 0); stageV(1, 1); stageK(1, 1);
  asm volatile("s_waitcnt vmcnt(0)" ::: "memory");
  BAR();

  int vb = 0;                                  // vb = s % 3
  for (int s = 0; s < 32; ++s) {
    const int vbW = (vb + 2 >= 3) ? vb - 1 : vb + 2;
    const int sc2 = (s + 2 < 32) ? s + 2 : 31; // clamp only overwrites dead buffers
    stageV(vbW, sc2);                          // V 3-buf: target dead, issue early
    f32x16 sacc;
    __builtin_amdgcn_s_setprio(1);
    qk(sacc, s & 1);
    __builtin_amdgcn_s_setprio(0);
    BAR();                                     // all waves done reading K(s)
    stageK(s & 1, sc2);                        // reuse K(s) slot for K(s+2)

    u64 mw = pmrow[s >> 1];
    u32 pw = (u32)(mw >> ((s & 1) * 32));      // KEEP bits for this 32-kv tile
    u32 halfm = pw >> (4 * hi);
    asm volatile("s_nop 7\n\ts_nop 7");
    u32 Wp[4][2];
#pragma unroll
    for (int t2 = 0; t2 < 4; ++t2) {
      float e[4];
#pragma unroll
      for (int j = 0; j < 4; ++j) {
        float ev = fexp2(sacc[4 * t2 + j]);
        int km;
        asm("v_bfe_i32 %0, %1, %2, 1" : "=v"(km) : "v"(halfm), "n"(8 * t2 + j));
        e[j] = __uint_as_float(__float_as_uint(ev) & (u32)km);
      }
      lp += (e[0] + e[1]) + (e[2] + e[3]);
      Wp[t2][0] = cvtpk(e[0], e[1]);
      Wp[t2][1] = cvtpk(e[2], e[3]);
    }
    s16x8 pa[2];
#pragma unroll
    for (int kq = 0; kq < 2; ++kq) {
      u32 s0 = hi ? Wp[2 * kq][0] : Wp[2 * kq + 1][0];
      u32 s1 = hi ? Wp[2 * kq][1] : Wp[2 * kq + 1][1];
      u32 r0 = (u32)__shfl_xor((int)s0, 32);
      u32 r1 = (u32)__shfl_xor((int)s1, 32);
      u32 o0 = hi ? Wp[2 * kq + 1][0] : Wp[2 * kq][0];
      u32 o1 = hi ? Wp[2 * kq + 1][1] : Wp[2 * kq][1];
      u32x4 wv;
      wv.x = hi ? r0 : o0;
      wv.y = hi ? r1 : o1;
      wv.z = hi ? o0 : r0;
      wv.w = hi ? o1 : r1;
      pa[kq] = __builtin_bit_cast(s16x8, wv);
    }
    asm volatile("s_nop 3");
    const char* Vc = smem + 32768 + (t * 3 + vb) * 8192;
    __builtin_amdgcn_s_setprio(1);
#pragma unroll
    for (int kq = 0; kq < 2; ++kq)
#pragma unroll
      for (int dt = 0; dt < 4; ++dt) {
        int vrow = dt * 32 + ql;
        s16x8 vf = *(const s16x8*)(Vc + vrow * 64 + (((2 * kq + hi) ^ (vrow & 3)) << 4));
        mfma32(oacc[dt], pa[kq], vf);
      }
    __builtin_amdgcn_s_setprio(0);
    asm volatile("s_waitcnt vmcnt(2)" ::: "memory");  // lands K(s+1)+V(s+2); K(s+2) in flight
    BAR();
    vb = (vb + 1 == 3) ? 0 : vb + 1;
  }

  // epilogue: drain staging, combine streams via LDS scratch (exact: O=(O0+O1)/(l0+l1))
  asm volatile("s_waitcnt vmcnt(0)" ::: "memory");
  __syncthreads();
  asm volatile("s_nop 7\n\ts_nop 7");
  lp += __shfl_xor(lp, 32);                    // lanes ql, ql^32 hold complementary kv sets
  float* scr = (float*)smem;                   // oacc: 16 slots x 4KB; l at float ofs 16384
  if (lane < 32) scr[16384 + (t * 4 + ws) * 32 + lane] = lp;
  if (t == 1) {
    union { f32x16 v; f32x4 p[4]; } u;
#pragma unroll
    for (int dt = 0; dt < 4; ++dt) {
      u.v = oacc[dt];
#pragma unroll
      for (int pc = 0; pc < 4; ++pc)
        *(f32x4*)(scr + ((dt * 4 + pc) * 256 + ws * 64 + lane) * 4) = u.p[pc];
    }
  }
  __syncthreads();
  if (t == 0) {
    float rl[16];
#pragma unroll
    for (int reg = 0; reg < 16; ++reg) {
      int qr = (reg & 3) + 8 * (reg >> 2) + 4 * hi;
      rl[reg] = 1.f / (scr[16384 + ws * 32 + qr] + scr[16384 + (4 + ws) * 32 + qr]);
    }
#pragma unroll
    for (int dt = 0; dt < 4; ++dt) {
      union { f32x16 v; f32x4 p[4]; } o2;
#pragma unroll
      for (int pc = 0; pc < 4; ++pc)
        o2.p[pc] = *(const f32x4*)(scr + ((dt * 4 + pc) * 256 + ws * 64 + lane) * 4);
#pragma unroll
      for (int reg = 0; reg < 16; ++reg) {
        int qr = (reg & 3) + 8 * (reg >> 2) + 4 * hi;
        size_t trow = (size_t)(b * 2048 + q0 + ws * 32 + qr);
        Ob[trow * 1024 + h * 128 + dt * 32 + ql] =
            f2bf((oacc[dt][reg] + o2.v[reg]) * rl[reg]);
      }
    }
  }
}

// ---------------- launcher ----------------
extern "C" void kernel_launch(void* const* d_in, const int* in_sizes, int n_in,
                              void* d_out, int out_size, void* d_ws, size_t ws_size,
                              hipStream_t stream) {
  (void)in_sizes; (void)n_in; (void)out_size; (void)ws_size;
  const float* x    = (const float*)d_in[0];
  const int*   am   = (const int*)d_in[1];
  const float* qkvw = (const float*)d_in[2];
  const float* qkvb = (const float*)d_in[3];
  const float* qw   = (const float*)d_in[4];
  const float* qb   = (const float*)d_in[5];
  const float* kw   = (const float*)d_in[6];
  const float* kb   = (const float*)d_in[7];
  const float* vw   = (const float*)d_in[8];
  const float* vb   = (const float*)d_in[9];
  const float* ow   = (const float*)d_in[10];
  const float* ob   = (const float*)d_in[11];

  char* p = (char*)d_ws;
  auto take = [&](size_t n) { char* r = p; p += (n + 255) & ~(size_t)255; return r; };
  u16* xb    = (u16*)take(8192ull * 1024 * 2);        // also reused as attention output
  u16* qkvwT = (u16*)take(1024ull * 3072 * 2);
  u16* wb4   = (u16*)take(4ull * 1048576 * 2);        // qwb,kwb,vwb,owb
  u16* comb3 = (u16*)take(3ull * 1048576 * 2);        // comb_q (pre-scaled), comb_k, comb_v
  float* cb3 = (float*)take(3ull * 1024 * 4);
  u16* QK2   = (u16*)take(8192ull * 2048 * 2);        // fused [Q|K] (8192 x 2048)
  u16* V2t   = (u16*)take(8192ull * 1024 * 2);
  u64* pm    = (u64*)take(2048ull * 32 * 8);
  u16* Obuf  = xb;                                    // alias: xb dead after projections

  // fused prep (x->bf16, weights->bf16, qkv_w^T, combined bias, mask pack)
  prep<<<18176, 256, 0, stream>>>(x, xb, qw, kw, vw, ow, wb4, qkvw, qkvwT,
                                  qkvb, qb, kb, vb, cb3, am, pm);
  // combined weights: comb_z[o][i] = sum_m W_z[o][m] * qkv_w[z*1024+m][i]; z==0 scaled
  gemm_nt<u16, false><<<dim3(64, 1, 3), 256, 0, stream>>>(
      wb4, 1024, 1048576, qkvwT, 3072, 1024, comb3, 1024, 1048576, nullptr, 0, 8, 1024, kQScale);
  // fused Q|K projection: 512 balanced blocks, 2/CU
  gemm_qk<<<512, 512, 0, stream>>>(xb, comb3, cb3, QK2);
  // V transposed: V2t[o][t] = comb_v[o]·x[t] + cb_v[o]  (bias per row)
  gemm_nt<u16, true><<<dim3(512, 1, 1), 256, 0, stream>>>(
      comb3 + 2 * 1048576, 1024, 0, xb, 1024, 0, V2t, 8192, 0, cb3 + 2048, 0, 64, 1024, 1.f);
  attn_fwd<<<512, 512, 0, stream>>>(QK2, QK2 + 1024, 2048, V2t, pm, Obuf);
  // out = O @ out_w^T + out_b  (fp32 output)
  gemm_nt<float, false><<<dim3(512, 1, 1), 256, 0, stream>>>(
      Obuf, 1024, 0, wb4 + 3 * 1048576, 1024, 0, (float*)d_out, 1024, 0, ob, 0, 8, 1024, 1.f);
}

// Round 12
// 240.168 us; speedup vs baseline: 1.4600x; 1.4600x over previous
//
#include <hip/hip_runtime.h>
#include <stdint.h>

typedef unsigned short u16;
typedef unsigned int u32;
typedef unsigned long long u64;
using f32x4 = __attribute__((ext_vector_type(4))) float;
using f32x16 = __attribute__((ext_vector_type(16))) float;
using s16x8 = __attribute__((ext_vector_type(8))) short;
using u16x4 = __attribute__((ext_vector_type(4))) unsigned short;
using u32x4 = __attribute__((ext_vector_type(4))) u32;

static constexpr float kQScale = (float)(0.08838834764831845 * 1.4426950408889634);  // SCALE*log2(e)

__device__ __forceinline__ u16 f2bf(float f) {
  uint32_t u = __float_as_uint(f);
  u += 0x7fffu + ((u >> 16) & 1u);   // RNE
  return (u16)(u >> 16);
}

__device__ __forceinline__ float fexp2(float x) {
#if __has_builtin(__builtin_amdgcn_exp2f)
  return __builtin_amdgcn_exp2f(x);
#else
  return exp2f(x);
#endif
}

__device__ __forceinline__ u32 cvtpk(float lo, float hi) {
  u32 r;
  asm("v_cvt_pk_bf16_f32 %0, %1, %2" : "=v"(r) : "v"(lo), "v"(hi));
  return r;
}

// 16x16x32 bf16 MFMA (D=C tied): C/D col=lane&15, row=4*(lane>>4)+reg [m89/m91].
__device__ __forceinline__ void mfma16(f32x4& d, s16x8 a, s16x8 b) {
  asm volatile("v_mfma_f32_16x16x32_bf16 %0, %1, %2, %0" : "+v"(d) : "v"(a), "v"(b));
}
// 32x32x16 bf16 MFMA: A row=lane&31,k=8*(lane>>5)+j; B col=lane&31;
// C/D col=lane&31, row=(reg&3)+8*(reg>>2)+4*(lane>>5) [m74/m101].
__device__ __forceinline__ void mfma32(f32x16& d, s16x8 a, s16x8 b) {
  asm volatile("v_mfma_f32_32x32x16_bf16 %0, %1, %2, %0" : "+v"(d) : "v"(a), "v"(b));
}
__device__ __forceinline__ f32x16 mfma32_z(s16x8 a, s16x8 b) {
  f32x16 d;
  asm volatile("v_mfma_f32_32x32x16_bf16 %0, %1, %2, 0" : "=&v"(d) : "v"(a), "v"(b));
  return d;
}

// async global->LDS, 16B per lane; LDS dest = wave-uniform base + lane*16 (m104).
__device__ __forceinline__ void g2lds16(const void* g, void* l) {
  __builtin_amdgcn_global_load_lds(
      (__attribute__((address_space(1))) void*)(uintptr_t)g,
      (__attribute__((address_space(3))) void*)(uint32_t)(uintptr_t)l, 16, 0, 0);
}

#define BAR() asm volatile("s_barrier" ::: "memory")

// ---------------- fused prep: x->bf16 | weights->bf16 | qkv_w^T | comb bias | mask pack ----
__global__ __launch_bounds__(256) void prep(const float* __restrict__ x, u16* __restrict__ xb,
                                            const float* __restrict__ qw, const float* __restrict__ kw,
                                            const float* __restrict__ vw, const float* __restrict__ ow,
                                            u16* __restrict__ wb4,
                                            const float* __restrict__ qkvw, u16* __restrict__ qkvwT,
                                            const float* __restrict__ qkvb, const float* __restrict__ qb,
                                            const float* __restrict__ kb, const float* __restrict__ vb,
                                            float* __restrict__ cb3,
                                            const int* __restrict__ am, u64* __restrict__ pm) {
  __shared__ u16 tile[32][33];
  const int bid = blockIdx.x, tid = threadIdx.x;
  if (bid < 8192) {                       // x (8192x1024 f32) -> bf16
    int i = (bid * 256 + tid) * 4;
    f32x4 v = *(const f32x4*)(x + i);
    u16x4 o = {f2bf(v.x), f2bf(v.y), f2bf(v.z), f2bf(v.w)};
    *(u16x4*)(xb + i) = o;
  } else if (bid < 12288) {               // 4 weights (1024^2 f32) -> bf16, contiguous
    int idx = bid - 8192;
    int z = idx >> 10;
    const float* in = z == 0 ? qw : z == 1 ? kw : z == 2 ? vw : ow;
    int i = ((idx & 1023) * 256 + tid) * 4;
    f32x4 v = *(const f32x4*)(in + i);
    u16x4 o = {f2bf(v.x), f2bf(v.y), f2bf(v.z), f2bf(v.w)};
    *(u16x4*)(wb4 + (size_t)z * 1048576 + i) = o;
  } else if (bid < 15360) {               // qkv_w (3072x1024) -> qkv_wT (1024x3072) bf16
    int idx = bid - 12288;
    int bx = idx & 31, by = idx >> 5;
    int tx = tid & 31, ty = tid >> 5;
#pragma unroll
    for (int k = 0; k < 4; ++k)
      tile[ty + k * 8][tx] = f2bf(qkvw[(size_t)(by * 32 + ty + k * 8) * 1024 + bx * 32 + tx]);
    __syncthreads();
#pragma unroll
    for (int k = 0; k < 4; ++k)
      qkvwT[(size_t)(bx * 32 + ty + k * 8) * 3072 + by * 32 + tx] = tile[tx][ty + k * 8];
  } else if (bid < 16128) {               // combined bias (fp32 exact); z==0 scaled
    int idx = bid - 15360;
    int z = idx >> 8;
    const float* w = z == 0 ? qw : (z == 1 ? kw : vw);
    const float* ba = z == 0 ? qb : (z == 1 ? kb : vb);
    const float* bi = qkvb + z * 1024;
    int o = (idx & 255) * 4 + (tid >> 6);
    int lane = tid & 63;
    float s = 0.f;
    for (int m = lane; m < 1024; m += 64) s += w[o * 1024 + m] * bi[m];
#pragma unroll
    for (int d = 1; d < 64; d <<= 1) s += __shfl_xor(s, d);
    if (lane == 0) {
      float fin = s + ba[o];
      if (z == 0) fin *= kQScale;
      cb3[z * 1024 + o] = fin;
    }
  } else {                                // mask -> bit-packed KEEP rows (2048 x 32 u64)
    int row = bid - 16128;
    int wv = tid >> 6, lane = tid & 63;
#pragma unroll
    for (int i = 0; i < 8; ++i) {
      int word = wv * 8 + i;
      u64 b = __ballot(am[(size_t)row * 2048 + word * 64 + lane] == 0);
      if (lane == 0) pm[(size_t)row * 32 + word] = b;
    }
  }
}

// ---------------- NT GEMM 128^2 (m97-style) ----------------
template <typename OUT_T, bool BIAS_PER_ROW>
__global__ __launch_bounds__(256, 2) void gemm_nt(const u16* __restrict__ A, int lda, long bsA,
                                                  const u16* __restrict__ B, int ldb, long bsB,
                                                  OUT_T* __restrict__ C, int ldc, long bsC,
                                                  const float* __restrict__ bias, long bsBias,
                                                  int NtilesN, int K, float scale_z0) {
  __shared__ __align__(16) u16 As[128 * 64];
  __shared__ __align__(16) u16 Bs[128 * 64];
  const int z = blockIdx.z;
  const float sc = (z == 0) ? scale_z0 : 1.f;
  A += (size_t)z * bsA; B += (size_t)z * bsB; C += (size_t)z * bsC;
  if (bias) bias += (size_t)z * bsBias;
  const int tm = blockIdx.x / NtilesN, tn = blockIdx.x % NtilesN;
  const int tid = threadIdx.x, lane = tid & 63, w = tid >> 6;
  const int wm = w >> 1, wn = w & 1;
  const int q = lane & 15, g = lane >> 4;
  f32x4 acc[4][4] = {};

  const u16* Ab = A + (size_t)(tm * 128 + (tid >> 3)) * lda + ((tid & 7) << 3);
  const u16* Bb = B + (size_t)(tn * 128 + (tid >> 3)) * ldb + ((tid & 7) << 3);
  char* AsW = (char*)As + (w << 10);
  char* BsW = (char*)Bs + (w << 10);

  for (int k0 = 0; k0 < K; k0 += 64) {
#pragma unroll
    for (int it = 0; it < 4; ++it) {
      g2lds16(Ab + (size_t)(it * 32) * lda + k0, AsW + it * 4096);
      g2lds16(Bb + (size_t)(it * 32) * ldb + k0, BsW + it * 4096);
    }
    __syncthreads();
#pragma unroll
    for (int kk = 0; kk < 2; ++kk) {
      s16x8 af[4], bf[4];
#pragma unroll
      for (int i = 0; i < 4; ++i)
        af[i] = *(const s16x8*)((const char*)As + (wm * 64 + i * 16 + q) * 128 + kk * 64 + g * 16);
#pragma unroll
      for (int i = 0; i < 4; ++i)
        bf[i] = *(const s16x8*)((const char*)Bs + (wn * 64 + i * 16 + q) * 128 + kk * 64 + g * 16);
#pragma unroll
      for (int mf = 0; mf < 4; ++mf)
#pragma unroll
        for (int nf = 0; nf < 4; ++nf) mfma16(acc[mf][nf], af[mf], bf[nf]);
    }
    __syncthreads();
  }
  asm volatile("s_nop 7\n\ts_nop 7");
#pragma unroll
  for (int mf = 0; mf < 4; ++mf)
#pragma unroll
    for (int nf = 0; nf < 4; ++nf) {
      const int row = tm * 128 + wm * 64 + mf * 16 + g * 4;
      const int col = tn * 128 + wn * 64 + nf * 16 + q;
      float bc = (!BIAS_PER_ROW && bias) ? bias[col] : 0.f;
#pragma unroll
      for (int r = 0; r < 4; ++r) {
        float v = acc[mf][nf][r] * sc;
        if (bias) v += BIAS_PER_ROW ? bias[row + r] : bc;
        if constexpr (sizeof(OUT_T) == 2)
          C[(size_t)(row + r) * ldc + col] = (OUT_T)f2bf(v);
        else
          C[(size_t)(row + r) * ldc + col] = (OUT_T)v;
      }
    }
}

// ------- QK projection: 256x128-tile, 8-wave (4Mx2N), m97 flow, 48KB LDS, 2 blocks/CU ----
__global__ __launch_bounds__(512, 4) void gemm_qk(const u16* __restrict__ A,
                                                  const u16* __restrict__ B,
                                                  const float* __restrict__ bias,
                                                  u16* __restrict__ C) {
  __shared__ __align__(16) u16 As[256 * 64];   // 32KB
  __shared__ __align__(16) u16 Bs[128 * 64];   // 16KB
  const int bid = blockIdx.x;
  const int wgid = (bid & 7) * 64 + (bid >> 3);        // XCD-contiguous (512 % 8 == 0)
  const int tm = wgid >> 4, tn = wgid & 15;
  const int tid = threadIdx.x, lane = tid & 63, w = tid >> 6;
  const int wm = w >> 1, wn = w & 1;
  const int q = lane & 15, g = lane >> 4, qk = q & 7;
  f32x4 acc[4][4] = {};

  const int srow = tid >> 3, sch = tid & 7;
  const int gcol = (sch ^ (srow & 7)) << 3;
  const u16* Abase = A + (size_t)(tm * 256 + srow) * 1024 + gcol;
  const u16* Bbase = B + (size_t)(tn * 128 + srow) * 1024 + gcol;
  char* AsW = (char*)As + (w << 10);
  char* BsW = (char*)Bs + (w << 10);

  for (int k0 = 0; k0 < 1024; k0 += 64) {
#pragma unroll
    for (int it = 0; it < 4; ++it)
      g2lds16(Abase + (size_t)(it * 64) * 1024 + k0, AsW + it * 8192);
#pragma unroll
    for (int it = 0; it < 2; ++it)
      g2lds16(Bbase + (size_t)(it * 64) * 1024 + k0, BsW + it * 8192);
    __syncthreads();
#pragma unroll
    for (int kk = 0; kk < 2; ++kk) {
      s16x8 af[4], bf[4];
#pragma unroll
      for (int i = 0; i < 4; ++i)
        af[i] = *(const s16x8*)((const char*)As + (wm * 64 + i * 16 + q) * 128 +
                                ((((kk << 2) + g) ^ qk) << 4));
#pragma unroll
      for (int i = 0; i < 4; ++i)
        bf[i] = *(const s16x8*)((const char*)Bs + (wn * 64 + i * 16 + q) * 128 +
                                ((((kk << 2) + g) ^ qk) << 4));
      __builtin_amdgcn_s_setprio(1);
#pragma unroll
      for (int mf = 0; mf < 4; ++mf)
#pragma unroll
        for (int nf = 0; nf < 4; ++nf) mfma16(acc[mf][nf], af[mf], bf[nf]);
      __builtin_amdgcn_s_setprio(0);
    }
    __syncthreads();
  }
  asm volatile("s_nop 7\n\ts_nop 7");
#pragma unroll
  for (int mf = 0; mf < 4; ++mf) {
    const int row = tm * 256 + wm * 64 + mf * 16 + g * 4;
#pragma unroll
    for (int nf = 0; nf < 4; ++nf) {
      const int col = tn * 128 + wn * 64 + nf * 16 + q;
      const float bc = bias[col];
#pragma unroll
      for (int r = 0; r < 4; ++r)
        C[(size_t)(row + r) * 2048 + col] = f2bf(acc[mf][nf][r] + bc);
    }
  }
}

// ---------------- flash attention: pipelined QK(s+1) ∥ softmax(s), in-register P ---------
// (R9-proven structure; prologue drain fixed to vmcnt(0) to close the K(1) in-flight race.)
__global__ __launch_bounds__(256, 2) void attn_fwd(const u16* __restrict__ Qb, const u16* __restrict__ Kb,
                                                   int ldq, const u16* __restrict__ Vt,
                                                   const u64* __restrict__ pmask,
                                                   u16* __restrict__ Ob) {
  __shared__ __align__(16) char K_lds[2][16384];  // [64 kv][128 d], 16B-chunk XOR (kv&15)
  __shared__ __align__(16) char V_lds[3][16384];  // [128 d][64 kv], chunk XOR (d&7)
  const int n = blockIdx.x;
  const int slot = n >> 3;
  const int grp = (n & 7) * 4 + (slot >> 4);
  const int qt = slot & 15;
  const int h = grp & 7, b = grp >> 3;
  const int tid = threadIdx.x, w = tid >> 6, lane = tid & 63;
  const int ql = lane & 31;
  const int hi = lane >> 5;
  const int q0 = qt * 128;

  s16x8 qf[8];
  const u16* qrow = Qb + (size_t)(b * 2048 + q0 + w * 32 + ql) * ldq + h * 128 + 8 * hi;
#pragma unroll
  for (int kd = 0; kd < 8; ++kd) qf[kd] = *(const s16x8*)(qrow + 16 * kd);

  u32x4 ov = {0x3F803F80u, 0x3F803F80u, 0x3F803F80u, 0x3F803F80u};
  const s16x8 ones = __builtin_bit_cast(s16x8, ov);

  f32x16 oacc[4] = {};   // dt: O[q=crow(reg,hi)][d = dt*32+ql]
  f32x16 lacc = {};      // l[q=crow(reg,hi)] in every column

  const int ksr = tid >> 4, ksc = tid & 15;  // K staging
  const int vsr = tid >> 3, vsc = tid & 7;   // V staging
  const int sw = ql & 15;                    // K read swizzle key
  const u64* pmrow = pmask + (size_t)(q0 + w * 32 + ql) * 32;

  auto stageK = [&](int buf, int s2) {
    const int kv0 = s2 * 64;
    char* kb = K_lds[buf] + (w << 10);
#pragma unroll
    for (int it = 0; it < 4; ++it) {
      int kr = it * 16 + ksr;
      g2lds16(Kb + (size_t)(b * 2048 + kv0 + kr) * ldq + h * 128 + ((ksc ^ (kr & 15)) << 3),
              kb + it * 4096);
    }
  };
  auto stageV = [&](int buf, int s2) {
    const int kv0 = s2 * 64;
    char* vb = V_lds[buf] + (w << 10);
#pragma unroll
    for (int it = 0; it < 4; ++it) {
      int vr = it * 32 + vsr;
      g2lds16(Vt + (size_t)(h * 128 + vr) * 8192 + b * 2048 + kv0 + ((vsc ^ (vr & 7)) << 3),
              vb + it * 4096);
    }
  };
  auto qk = [&](f32x16& d0, f32x16& d1, int kbuf) {
    const char* Kc = K_lds[kbuf];
#pragma unroll
    for (int kd = 0; kd < 8; ++kd) {
      int c = (2 * kd + hi) ^ sw;
      s16x8 kf0 = *(const s16x8*)(Kc + ql * 256 + (c << 4));
      s16x8 kf1 = *(const s16x8*)(Kc + (32 + ql) * 256 + (c << 4));
      if (kd == 0) { d0 = mfma32_z(kf0, qf[0]); d1 = mfma32_z(kf1, qf[0]); }
      else         { mfma32(d0, kf0, qf[kd]);   mfma32(d1, kf1, qf[kd]); }
    }
  };

  auto body = [&](f32x16& c0, f32x16& c1, f32x16& n0, f32x16& n1, int s, int vbR, int vbW) {
    u64 pw = pmrow[s];                         // KEEP bits
    const int sc2 = (s + 2 < 32) ? s + 2 : 31;
    stageK(s & 1, sc2);
    stageV(vbW, sc2);
    if (s + 1 < 32) qk(n0, n1, (s + 1) & 1);
    const char* Vc = V_lds[vbR];
    s16x8 pa[2];
#pragma unroll
    for (int half = 0; half < 2; ++half) {
      u32 halfm = (u32)(pw >> (32 * half + 4 * hi));
      u32 Wp[4][2];
#pragma unroll
      for (int t = 0; t < 4; ++t) {
        float e[4];
#pragma unroll
        for (int j = 0; j < 4; ++j) {
          float ev = fexp2(half == 0 ? c0[4 * t + j] : c1[4 * t + j]);
          int km;
          asm("v_bfe_i32 %0, %1, %2, 1" : "=v"(km) : "v"(halfm), "n"(8 * t + j));
          e[j] = __uint_as_float(__float_as_uint(ev) & (u32)km);
        }
        Wp[t][0] = cvtpk(e[0], e[1]);
        Wp[t][1] = cvtpk(e[2], e[3]);
      }
#pragma unroll
      for (int kq = 0; kq < 2; ++kq) {
        u32 s0 = hi ? Wp[2 * kq][0] : Wp[2 * kq + 1][0];
        u32 s1 = hi ? Wp[2 * kq][1] : Wp[2 * kq + 1][1];
        u32 r0 = (u32)__shfl_xor((int)s0, 32);
        u32 r1 = (u32)__shfl_xor((int)s1, 32);
        u32 o0 = hi ? Wp[2 * kq + 1][0] : Wp[2 * kq][0];
        u32 o1 = hi ? Wp[2 * kq + 1][1] : Wp[2 * kq][1];
        u32x4 wv;
        wv.x = hi ? r0 : o0;
        wv.y = hi ? r1 : o1;
        wv.z = hi ? o0 : r0;
        wv.w = hi ? o1 : r1;
        pa[kq] = __builtin_bit_cast(s16x8, wv);
      }
      asm volatile("s_nop 3");
      __builtin_amdgcn_s_setprio(1);
#pragma unroll
      for (int kq = 0; kq < 2; ++kq) {
        const int ks = 2 * half + kq;
#pragma unroll
        for (int dt = 0; dt < 4; ++dt) {
          int vrow = dt * 32 + ql;
          s16x8 vf = *(const s16x8*)(Vc + vrow * 128 + (((2 * ks + hi) ^ (vrow & 7)) << 4));
          mfma32(oacc[dt], pa[kq], vf);
        }
        mfma32(lacc, pa[kq], ones);
      }
      __builtin_amdgcn_s_setprio(0);
    }
    asm volatile("s_waitcnt vmcnt(4)" ::: "memory");  // own-iter 8 stages: 4 may remain in flight
    BAR();
  };

  // prologue: KV(0), KV(1); FULL drain (K(1) is read by body-0's look-ahead qk) — race fix
  stageK(0, 0); stageV(0, 0); stageK(1, 1); stageV(1, 1);
  asm volatile("s_waitcnt vmcnt(0)" ::: "memory");
  BAR();
  f32x16 sA0, sA1, sB0, sB1;
  qk(sA0, sA1, 0);
  BAR();

  int vb = 0;
  for (int s2 = 0; s2 < 16; ++s2) {
    const int s = 2 * s2;
    const int vb1 = (vb + 1 == 3) ? 0 : vb + 1;
    const int vb2 = (vb + 2 >= 3) ? vb - 1 : vb + 2;
    body(sA0, sA1, sB0, sB1, s, vb, vb2);
    body(sB0, sB1, sA0, sA1, s + 1, vb1, vb);
    vb = vb2;
  }

  asm volatile("s_nop 7\n\ts_nop 7");
#pragma unroll
  for (int dt = 0; dt < 4; ++dt)
#pragma unroll
    for (int reg = 0; reg < 16; ++reg) {
      int qr = (reg & 3) + 8 * (reg >> 2) + 4 * hi;
      size_t trow = (size_t)(b * 2048 + q0 + w * 32 + qr);
      Ob[trow * 1024 + h * 128 + dt * 32 + ql] = f2bf(oacc[dt][reg] / lacc[reg]);
    }
}

// ---------------- launcher ----------------
extern "C" void kernel_launch(void* const* d_in, const int* in_sizes, int n_in,
                              void* d_out, int out_size, void* d_ws, size_t ws_size,
                              hipStream_t stream) {
  (void)in_sizes; (void)n_in; (void)out_size; (void)ws_size;
  const float* x    = (const float*)d_in[0];
  const int*   am   = (const int*)d_in[1];
  const float* qkvw = (const float*)d_in[2];
  const float* qkvb = (const float*)d_in[3];
  const float* qw   = (const float*)d_in[4];
  const float* qb   = (const float*)d_in[5];
  const float* kw   = (const float*)d_in[6];
  const float* kb   = (const float*)d_in[7];
  const float* vw   = (const float*)d_in[8];
  const float* vb   = (const float*)d_in[9];
  const float* ow   = (const float*)d_in[10];
  const float* ob   = (const float*)d_in[11];

  char* p = (char*)d_ws;
  auto take = [&](size_t n) { char* r = p; p += (n + 255) & ~(size_t)255; return r; };
  u16* xb    = (u16*)take(8192ull * 1024 * 2);        // also reused as attention output
  u16* qkvwT = (u16*)take(1024ull * 3072 * 2);
  u16* wb4   = (u16*)take(4ull * 1048576 * 2);        // qwb,kwb,vwb,owb
  u16* comb3 = (u16*)take(3ull * 1048576 * 2);        // comb_q (pre-scaled), comb_k, comb_v
  float* cb3 = (float*)take(3ull * 1024 * 4);
  u16* QK2   = (u16*)take(8192ull * 2048 * 2);        // fused [Q|K] (8192 x 2048)
  u16* V2t   = (u16*)take(8192ull * 1024 * 2);
  u64* pm    = (u64*)take(2048ull * 32 * 8);
  u16* Obuf  = xb;                                    // alias: xb dead after projections

  // fused prep (x->bf16, weights->bf16, qkv_w^T, combined bias, mask pack)
  prep<<<18176, 256, 0, stream>>>(x, xb, qw, kw, vw, ow, wb4, qkvw, qkvwT,
                                  qkvb, qb, kb, vb, cb3, am, pm);
  // combined weights: comb_z[o][i] = sum_m W_z[o][m] * qkv_w[z*1024+m][i]; z==0 scaled
  gemm_nt<u16, false><<<dim3(64, 1, 3), 256, 0, stream>>>(
      wb4, 1024, 1048576, qkvwT, 3072, 1024, comb3, 1024, 1048576, nullptr, 0, 8, 1024, kQScale);
  // fused Q|K projection: 512 balanced blocks, 2/CU
  gemm_qk<<<512, 512, 0, stream>>>(xb, comb3, cb3, QK2);
  // V transposed: V2t[o][t] = comb_v[o]·x[t] + cb_v[o]  (bias per row)
  gemm_nt<u16, true><<<dim3(512, 1, 1), 256, 0, stream>>>(
      comb3 + 2 * 1048576, 1024, 0, xb, 1024, 0, V2t, 8192, 0, cb3 + 2048, 0, 64, 1024, 1.f);
  attn_fwd<<<512, 256, 0, stream>>>(QK2, QK2 + 1024, 2048, V2t, pm, Obuf);
  // out = O @ out_w^T + out_b  (fp32 output)
  gemm_nt<float, false><<<dim3(512, 1, 1), 256, 0, stream>>>(
      Obuf, 1024, 0, wb4 + 3 * 1048576, 1024, 0, (float*)d_out, 1024, 0, ob, 0, 8, 1024, 1.f);
}

// Round 13
// 238.396 us; speedup vs baseline: 1.4709x; 1.0074x over previous
//
#include <hip/hip_runtime.h>
#include <stdint.h>

typedef unsigned short u16;
typedef unsigned int u32;
typedef unsigned long long u64;
using f32x4 = __attribute__((ext_vector_type(4))) float;
using f32x16 = __attribute__((ext_vector_type(16))) float;
using s16x8 = __attribute__((ext_vector_type(8))) short;
using u16x4 = __attribute__((ext_vector_type(4))) unsigned short;
using u32x4 = __attribute__((ext_vector_type(4))) u32;

static constexpr float kQScale = (float)(0.08838834764831845 * 1.4426950408889634);  // SCALE*log2(e)

__device__ __forceinline__ u16 f2bf(float f) {
  uint32_t u = __float_as_uint(f);
  u += 0x7fffu + ((u >> 16) & 1u);   // RNE
  return (u16)(u >> 16);
}

__device__ __forceinline__ float fexp2(float x) {
#if __has_builtin(__builtin_amdgcn_exp2f)
  return __builtin_amdgcn_exp2f(x);
#else
  return exp2f(x);
#endif
}

__device__ __forceinline__ u32 cvtpk(float lo, float hi) {
  u32 r;
  asm("v_cvt_pk_bf16_f32 %0, %1, %2" : "=v"(r) : "v"(lo), "v"(hi));
  return r;
}

// 16x16x32 bf16 MFMA (D=C tied): C/D col=lane&15, row=4*(lane>>4)+reg [m89/m91].
__device__ __forceinline__ void mfma16(f32x4& d, s16x8 a, s16x8 b) {
  asm volatile("v_mfma_f32_16x16x32_bf16 %0, %1, %2, %0" : "+v"(d) : "v"(a), "v"(b));
}
// 32x32x16 bf16 MFMA: A row=lane&31,k=8*(lane>>5)+j; B col=lane&31;
// C/D col=lane&31, row=(reg&3)+8*(reg>>2)+4*(lane>>5) [m74/m101].
__device__ __forceinline__ void mfma32(f32x16& d, s16x8 a, s16x8 b) {
  asm volatile("v_mfma_f32_32x32x16_bf16 %0, %1, %2, %0" : "+v"(d) : "v"(a), "v"(b));
}
__device__ __forceinline__ f32x16 mfma32_z(s16x8 a, s16x8 b) {
  f32x16 d;
  asm volatile("v_mfma_f32_32x32x16_bf16 %0, %1, %2, 0" : "=&v"(d) : "v"(a), "v"(b));
  return d;
}

// async global->LDS, 16B per lane; LDS dest = wave-uniform base + lane*16 (m104).
__device__ __forceinline__ void g2lds16(const void* g, void* l) {
  __builtin_amdgcn_global_load_lds(
      (__attribute__((address_space(1))) void*)(uintptr_t)g,
      (__attribute__((address_space(3))) void*)(uint32_t)(uintptr_t)l, 16, 0, 0);
}

#define BAR() asm volatile("s_barrier" ::: "memory")

// ---------------- fused prep: x->bf16 | weights->bf16 | qkv_w^T | comb bias | mask pack ----
__global__ __launch_bounds__(256) void prep(const float* __restrict__ x, u16* __restrict__ xb,
                                            const float* __restrict__ qw, const float* __restrict__ kw,
                                            const float* __restrict__ vw, const float* __restrict__ ow,
                                            u16* __restrict__ wb4,
                                            const float* __restrict__ qkvw, u16* __restrict__ qkvwT,
                                            const float* __restrict__ qkvb, const float* __restrict__ qb,
                                            const float* __restrict__ kb, const float* __restrict__ vb,
                                            float* __restrict__ cb3,
                                            const int* __restrict__ am, u64* __restrict__ pm) {
  __shared__ u16 tile[32][33];
  const int bid = blockIdx.x, tid = threadIdx.x;
  if (bid < 8192) {                       // x (8192x1024 f32) -> bf16
    int i = (bid * 256 + tid) * 4;
    f32x4 v = *(const f32x4*)(x + i);
    u16x4 o = {f2bf(v.x), f2bf(v.y), f2bf(v.z), f2bf(v.w)};
    *(u16x4*)(xb + i) = o;
  } else if (bid < 12288) {               // 4 weights (1024^2 f32) -> bf16, contiguous
    int idx = bid - 8192;
    int z = idx >> 10;
    const float* in = z == 0 ? qw : z == 1 ? kw : z == 2 ? vw : ow;
    int i = ((idx & 1023) * 256 + tid) * 4;
    f32x4 v = *(const f32x4*)(in + i);
    u16x4 o = {f2bf(v.x), f2bf(v.y), f2bf(v.z), f2bf(v.w)};
    *(u16x4*)(wb4 + (size_t)z * 1048576 + i) = o;
  } else if (bid < 15360) {               // qkv_w (3072x1024) -> qkv_wT (1024x3072) bf16
    int idx = bid - 12288;
    int bx = idx & 31, by = idx >> 5;
    int tx = tid & 31, ty = tid >> 5;
#pragma unroll
    for (int k = 0; k < 4; ++k)
      tile[ty + k * 8][tx] = f2bf(qkvw[(size_t)(by * 32 + ty + k * 8) * 1024 + bx * 32 + tx]);
    __syncthreads();
#pragma unroll
    for (int k = 0; k < 4; ++k)
      qkvwT[(size_t)(bx * 32 + ty + k * 8) * 3072 + by * 32 + tx] = tile[tx][ty + k * 8];
  } else if (bid < 16128) {               // combined bias (fp32 exact); z==0 scaled
    int idx = bid - 15360;
    int z = idx >> 8;
    const float* w = z == 0 ? qw : (z == 1 ? kw : vw);
    const float* ba = z == 0 ? qb : (z == 1 ? kb : vb);
    const float* bi = qkvb + z * 1024;
    int o = (idx & 255) * 4 + (tid >> 6);
    int lane = tid & 63;
    float s = 0.f;
    for (int m = lane; m < 1024; m += 64) s += w[o * 1024 + m] * bi[m];
#pragma unroll
    for (int d = 1; d < 64; d <<= 1) s += __shfl_xor(s, d);
    if (lane == 0) {
      float fin = s + ba[o];
      if (z == 0) fin *= kQScale;
      cb3[z * 1024 + o] = fin;
    }
  } else {                                // mask -> bit-packed KEEP rows (2048 x 32 u64)
    int row = bid - 16128;
    int wv = tid >> 6, lane = tid & 63;
#pragma unroll
    for (int i = 0; i < 8; ++i) {
      int word = wv * 8 + i;
      u64 b = __ballot(am[(size_t)row * 2048 + word * 64 + lane] == 0);
      if (lane == 0) pm[(size_t)row * 32 + word] = b;
    }
  }
}

// ---------------- NT GEMM 128^2 (m97-style) ----------------
template <typename OUT_T, bool BIAS_PER_ROW>
__global__ __launch_bounds__(256, 2) void gemm_nt(const u16* __restrict__ A, int lda, long bsA,
                                                  const u16* __restrict__ B, int ldb, long bsB,
                                                  OUT_T* __restrict__ C, int ldc, long bsC,
                                                  const float* __restrict__ bias, long bsBias,
                                                  int NtilesN, int K, float scale_z0) {
  __shared__ __align__(16) u16 As[128 * 64];
  __shared__ __align__(16) u16 Bs[128 * 64];
  const int z = blockIdx.z;
  const float sc = (z == 0) ? scale_z0 : 1.f;
  A += (size_t)z * bsA; B += (size_t)z * bsB; C += (size_t)z * bsC;
  if (bias) bias += (size_t)z * bsBias;
  const int tm = blockIdx.x / NtilesN, tn = blockIdx.x % NtilesN;
  const int tid = threadIdx.x, lane = tid & 63, w = tid >> 6;
  const int wm = w >> 1, wn = w & 1;
  const int q = lane & 15, g = lane >> 4;
  f32x4 acc[4][4] = {};

  const u16* Ab = A + (size_t)(tm * 128 + (tid >> 3)) * lda + ((tid & 7) << 3);
  const u16* Bb = B + (size_t)(tn * 128 + (tid >> 3)) * ldb + ((tid & 7) << 3);
  char* AsW = (char*)As + (w << 10);
  char* BsW = (char*)Bs + (w << 10);

  for (int k0 = 0; k0 < K; k0 += 64) {
#pragma unroll
    for (int it = 0; it < 4; ++it) {
      g2lds16(Ab + (size_t)(it * 32) * lda + k0, AsW + it * 4096);
      g2lds16(Bb + (size_t)(it * 32) * ldb + k0, BsW + it * 4096);
    }
    __syncthreads();
#pragma unroll
    for (int kk = 0; kk < 2; ++kk) {
      s16x8 af[4], bf[4];
#pragma unroll
      for (int i = 0; i < 4; ++i)
        af[i] = *(const s16x8*)((const char*)As + (wm * 64 + i * 16 + q) * 128 + kk * 64 + g * 16);
#pragma unroll
      for (int i = 0; i < 4; ++i)
        bf[i] = *(const s16x8*)((const char*)Bs + (wn * 64 + i * 16 + q) * 128 + kk * 64 + g * 16);
#pragma unroll
      for (int mf = 0; mf < 4; ++mf)
#pragma unroll
        for (int nf = 0; nf < 4; ++nf) mfma16(acc[mf][nf], af[mf], bf[nf]);
    }
    __syncthreads();
  }
  asm volatile("s_nop 7\n\ts_nop 7");
#pragma unroll
  for (int mf = 0; mf < 4; ++mf)
#pragma unroll
    for (int nf = 0; nf < 4; ++nf) {
      const int row = tm * 128 + wm * 64 + mf * 16 + g * 4;
      const int col = tn * 128 + wn * 64 + nf * 16 + q;
      float bc = (!BIAS_PER_ROW && bias) ? bias[col] : 0.f;
#pragma unroll
      for (int r = 0; r < 4; ++r) {
        float v = acc[mf][nf][r] * sc;
        if (bias) v += BIAS_PER_ROW ? bias[row + r] : bc;
        if constexpr (sizeof(OUT_T) == 2)
          C[(size_t)(row + r) * ldc + col] = (OUT_T)f2bf(v);
        else
          C[(size_t)(row + r) * ldc + col] = (OUT_T)v;
      }
    }
}

// ------- QK projection: 256^2 8-phase schedule (m201 port). 256 blocks, 8 waves, 128KB LDS.
// Wave (wm,wn): rows {mh*128 + wm*64 ..+63}, cols {nh*128 + wn*32 ..+31}, mh,nh in {0,1}.
// Phase (mh,nh) reads exactly A-half mh / B-half nh => stage legality by phase:
//   buf0 (even kt): A0 dead after p1, B0 after p2, A1,B1 after p3 -> stage kt+2 at p2..p5.
//   buf1 (odd kt): halves staged at p6,p7 (prev iter: A0,B0) and p0,p1 (this: A1,B1).
// vmcnt(4) at p3,p7 only (drains all but the 2 youngest stages; every read's src landed).
__global__ __launch_bounds__(512, 1) void gemm_qk8(const u16* __restrict__ A,
                                                   const u16* __restrict__ B,
                                                   const float* __restrict__ bias,
                                                   u16* __restrict__ C) {
  __shared__ __align__(16) u16 Als[2][256 * 64];   // 64KB
  __shared__ __align__(16) u16 Bls[2][256 * 64];   // 64KB
  const int bid = blockIdx.x;                      // 32x8 tiles; bid&7 = tn = per-XCD B-panel
  const int tm = bid >> 3, tn = bid & 7;
  const int tid = threadIdx.x, lane = tid & 63, w = tid >> 6;
  const int wm = w >> 2, wn = w & 3;
  const int q = lane & 15, g = lane >> 4, qk7 = q & 7;
  f32x4 acc[8][4] = {};

  const int srow = tid >> 3, sch = tid & 7;
  const int gcol = (sch ^ (srow & 7)) << 3;        // pre-swizzled source (rule 21)
  const u16* Abase = A + (size_t)(tm * 256 + srow) * 1024 + gcol;
  const u16* Bbase = B + (size_t)(tn * 256 + srow) * 1024 + gcol;

  auto stage = [&](int buf, int isB, int half, int kt) {
    const u16* src = (isB ? Bbase : Abase) + (size_t)(half * 128) * 1024 + (kt << 6);
    char* d = (char*)(isB ? &Bls[buf][0] : &Als[buf][0]) + half * 16384 + (w << 10);
    g2lds16(src, d);
    g2lds16(src + (size_t)64 * 1024, d + 8192);
  };

#define VM4 asm volatile("s_waitcnt vmcnt(4)" ::: "memory")
#define NOW ((void)0)
#define PHASE(BUF, MH, NH, SBUF, SISB, SHALF, SKT, WAIT) do {                              \
    s16x8 af[4][2], bf[2][2];                                                              \
    _Pragma("unroll") for (int mf = 0; mf < 4; ++mf)                                       \
      _Pragma("unroll") for (int kk = 0; kk < 2; ++kk)                                     \
        af[mf][kk] = *(const s16x8*)((const char*)&Als[BUF][0] +                           \
            ((MH) * 128 + wm * 64 + mf * 16 + q) * 128 + ((((kk << 2) + g) ^ qk7) << 4));  \
    _Pragma("unroll") for (int nf = 0; nf < 2; ++nf)                                       \
      _Pragma("unroll") for (int kk = 0; kk < 2; ++kk)                                     \
        bf[nf][kk] = *(const s16x8*)((const char*)&Bls[BUF][0] +                           \
            ((NH) * 128 + wn * 32 + nf * 16 + q) * 128 + ((((kk << 2) + g) ^ qk7) << 4));  \
    stage(SBUF, SISB, SHALF, SKT);                                                         \
    BAR();                                                                                 \
    __builtin_amdgcn_s_setprio(1);                                                         \
    _Pragma("unroll") for (int mf = 0; mf < 4; ++mf)                                       \
      _Pragma("unroll") for (int nf = 0; nf < 2; ++nf)                                     \
        _Pragma("unroll") for (int kk = 0; kk < 2; ++kk)                                   \
          mfma16(acc[(MH) * 4 + mf][(NH) * 2 + nf], af[mf][kk], bf[nf][kk]);               \
    __builtin_amdgcn_s_setprio(0);                                                         \
    WAIT;                                                                                  \
    BAR();                                                                                 \
  } while (0)

  // prologue: buf0 = kt0 full (A0,B0,A1,B1), buf1 = kt1 A0,B0; drain all but last 4
  stage(0, 0, 0, 0); stage(0, 1, 0, 0); stage(0, 0, 1, 0); stage(0, 1, 1, 0);
  stage(1, 0, 0, 1); stage(1, 1, 0, 1);
  VM4;
  BAR();

  for (int i = 0; i < 8; ++i) {                    // 16 K-tiles, 2 per iter
    const int ktA = 2 * i + 1;                     // buf1 completion (A1,B1) for kt 2i+1
    const int kt2 = (2 * i + 2 <= 14) ? 2 * i + 2 : 14;   // clamp preserves parity (buf0)
    const int kt3 = (2 * i + 3 <= 15) ? 2 * i + 3 : 15;   // (buf1)
    PHASE(0, 0, 0, 1, 0, 1, ktA, NOW);
    PHASE(0, 0, 1, 1, 1, 1, ktA, NOW);
    PHASE(0, 1, 0, 0, 0, 0, kt2, NOW);
    PHASE(0, 1, 1, 0, 1, 0, kt2, VM4);
    PHASE(1, 0, 0, 0, 0, 1, kt2, NOW);
    PHASE(1, 0, 1, 0, 1, 1, kt2, NOW);
    PHASE(1, 1, 0, 1, 0, 0, kt3, NOW);
    PHASE(1, 1, 1, 1, 1, 0, kt3, VM4);
  }
#undef PHASE
#undef VM4
#undef NOW

  asm volatile("s_nop 7\n\ts_nop 7");
#pragma unroll
  for (int mh = 0; mh < 2; ++mh)
#pragma unroll
    for (int mf = 0; mf < 4; ++mf) {
      const int row = tm * 256 + mh * 128 + wm * 64 + mf * 16 + g * 4;
#pragma unroll
      for (int nh = 0; nh < 2; ++nh)
#pragma unroll
        for (int nf = 0; nf < 2; ++nf) {
          const int col = tn * 256 + nh * 128 + wn * 32 + nf * 16 + q;
          const float bc = bias[col];
#pragma unroll
          for (int r = 0; r < 4; ++r)
            C[(size_t)(row + r) * 2048 + col] = f2bf(acc[mh * 4 + mf][nh * 2 + nf][r] + bc);
        }
    }
}

// ---------------- flash attention: pipelined QK(s+1) ∥ softmax(s), in-register P ---------
__global__ __launch_bounds__(256, 2) void attn_fwd(const u16* __restrict__ Qb, const u16* __restrict__ Kb,
                                                   int ldq, const u16* __restrict__ Vt,
                                                   const u64* __restrict__ pmask,
                                                   u16* __restrict__ Ob) {
  __shared__ __align__(16) char K_lds[2][16384];  // [64 kv][128 d], 16B-chunk XOR (kv&15)
  __shared__ __align__(16) char V_lds[3][16384];  // [128 d][64 kv], chunk XOR (d&7)
  const int n = blockIdx.x;
  const int slot = n >> 3;
  const int grp = (n & 7) * 4 + (slot >> 4);
  const int qt = slot & 15;
  const int h = grp & 7, b = grp >> 3;
  const int tid = threadIdx.x, w = tid >> 6, lane = tid & 63;
  const int ql = lane & 31;
  const int hi = lane >> 5;
  const int q0 = qt * 128;

  s16x8 qf[8];
  const u16* qrow = Qb + (size_t)(b * 2048 + q0 + w * 32 + ql) * ldq + h * 128 + 8 * hi;
#pragma unroll
  for (int kd = 0; kd < 8; ++kd) qf[kd] = *(const s16x8*)(qrow + 16 * kd);

  u32x4 ov = {0x3F803F80u, 0x3F803F80u, 0x3F803F80u, 0x3F803F80u};
  const s16x8 ones = __builtin_bit_cast(s16x8, ov);

  f32x16 oacc[4] = {};   // dt: O[q=crow(reg,hi)][d = dt*32+ql]
  f32x16 lacc = {};      // l[q=crow(reg,hi)] in every column

  const int ksr = tid >> 4, ksc = tid & 15;  // K staging
  const int vsr = tid >> 3, vsc = tid & 7;   // V staging
  const int sw = ql & 15;                    // K read swizzle key
  const u64* pmrow = pmask + (size_t)(q0 + w * 32 + ql) * 32;

  auto stageK = [&](int buf, int s2) {
    const int kv0 = s2 * 64;
    char* kb = K_lds[buf] + (w << 10);
#pragma unroll
    for (int it = 0; it < 4; ++it) {
      int kr = it * 16 + ksr;
      g2lds16(Kb + (size_t)(b * 2048 + kv0 + kr) * ldq + h * 128 + ((ksc ^ (kr & 15)) << 3),
              kb + it * 4096);
    }
  };
  auto stageV = [&](int buf, int s2) {
    const int kv0 = s2 * 64;
    char* vb = V_lds[buf] + (w << 10);
#pragma unroll
    for (int it = 0; it < 4; ++it) {
      int vr = it * 32 + vsr;
      g2lds16(Vt + (size_t)(h * 128 + vr) * 8192 + b * 2048 + kv0 + ((vsc ^ (vr & 7)) << 3),
              vb + it * 4096);
    }
  };
  auto qk = [&](f32x16& d0, f32x16& d1, int kbuf) {
    const char* Kc = K_lds[kbuf];
#pragma unroll
    for (int kd = 0; kd < 8; ++kd) {
      int c = (2 * kd + hi) ^ sw;
      s16x8 kf0 = *(const s16x8*)(Kc + ql * 256 + (c << 4));
      s16x8 kf1 = *(const s16x8*)(Kc + (32 + ql) * 256 + (c << 4));
      if (kd == 0) { d0 = mfma32_z(kf0, qf[0]); d1 = mfma32_z(kf1, qf[0]); }
      else         { mfma32(d0, kf0, qf[kd]);   mfma32(d1, kf1, qf[kd]); }
    }
  };

  auto body = [&](f32x16& c0, f32x16& c1, f32x16& n0, f32x16& n1, int s, int vbR, int vbW) {
    u64 pw = pmrow[s];                         // KEEP bits
    const int sc2 = (s + 2 < 32) ? s + 2 : 31;
    stageK(s & 1, sc2);
    stageV(vbW, sc2);
    if (s + 1 < 32) qk(n0, n1, (s + 1) & 1);
    const char* Vc = V_lds[vbR];
    s16x8 pa[2];
#pragma unroll
    for (int half = 0; half < 2; ++half) {
      u32 halfm = (u32)(pw >> (32 * half + 4 * hi));
      u32 Wp[4][2];
#pragma unroll
      for (int t = 0; t < 4; ++t) {
        float e[4];
#pragma unroll
        for (int j = 0; j < 4; ++j) {
          float ev = fexp2(half == 0 ? c0[4 * t + j] : c1[4 * t + j]);
          int km;
          asm("v_bfe_i32 %0, %1, %2, 1" : "=v"(km) : "v"(halfm), "n"(8 * t + j));
          e[j] = __uint_as_float(__float_as_uint(ev) & (u32)km);
        }
        Wp[t][0] = cvtpk(e[0], e[1]);
        Wp[t][1] = cvtpk(e[2], e[3]);
      }
#pragma unroll
      for (int kq = 0; kq < 2; ++kq) {
        u32 s0 = hi ? Wp[2 * kq][0] : Wp[2 * kq + 1][0];
        u32 s1 = hi ? Wp[2 * kq][1] : Wp[2 * kq + 1][1];
        u32 r0 = (u32)__shfl_xor((int)s0, 32);
        u32 r1 = (u32)__shfl_xor((int)s1, 32);
        u32 o0 = hi ? Wp[2 * kq + 1][0] : Wp[2 * kq][0];
        u32 o1 = hi ? Wp[2 * kq + 1][1] : Wp[2 * kq][1];
        u32x4 wv;
        wv.x = hi ? r0 : o0;
        wv.y = hi ? r1 : o1;
        wv.z = hi ? o0 : r0;
        wv.w = hi ? o1 : r1;
        pa[kq] = __builtin_bit_cast(s16x8, wv);
      }
      asm volatile("s_nop 3");
      __builtin_amdgcn_s_setprio(1);
#pragma unroll
      for (int kq = 0; kq < 2; ++kq) {
        const int ks = 2 * half + kq;
#pragma unroll
        for (int dt = 0; dt < 4; ++dt) {
          int vrow = dt * 32 + ql;
          s16x8 vf = *(const s16x8*)(Vc + vrow * 128 + (((2 * ks + hi) ^ (vrow & 7)) << 4));
          mfma32(oacc[dt], pa[kq], vf);
        }
        mfma32(lacc, pa[kq], ones);
      }
      __builtin_amdgcn_s_setprio(0);
    }
    asm volatile("s_waitcnt vmcnt(4)" ::: "memory");  // own-iter 8 stages: 4 may remain in flight
    BAR();
  };

  // prologue: KV(0), KV(1); FULL drain (K(1) is read by body-0's look-ahead qk)
  stageK(0, 0); stageV(0, 0); stageK(1, 1); stageV(1, 1);
  asm volatile("s_waitcnt vmcnt(0)" ::: "memory");
  BAR();
  f32x16 sA0, sA1, sB0, sB1;
  qk(sA0, sA1, 0);
  BAR();

  int vb = 0;
  for (int s2 = 0; s2 < 16; ++s2) {
    const int s = 2 * s2;
    const int vb1 = (vb + 1 == 3) ? 0 : vb + 1;
    const int vb2 = (vb + 2 >= 3) ? vb - 1 : vb + 2;
    body(sA0, sA1, sB0, sB1, s, vb, vb2);
    body(sB0, sB1, sA0, sA1, s + 1, vb1, vb);
    vb = vb2;
  }

  asm volatile("s_nop 7\n\ts_nop 7");
#pragma unroll
  for (int dt = 0; dt < 4; ++dt)
#pragma unroll
    for (int reg = 0; reg < 16; ++reg) {
      int qr = (reg & 3) + 8 * (reg >> 2) + 4 * hi;
      size_t trow = (size_t)(b * 2048 + q0 + w * 32 + qr);
      Ob[trow * 1024 + h * 128 + dt * 32 + ql] = f2bf(oacc[dt][reg] / lacc[reg]);
    }
}

// ---------------- launcher ----------------
extern "C" void kernel_launch(void* const* d_in, const int* in_sizes, int n_in,
                              void* d_out, int out_size, void* d_ws, size_t ws_size,
                              hipStream_t stream) {
  (void)in_sizes; (void)n_in; (void)out_size; (void)ws_size;
  const float* x    = (const float*)d_in[0];
  const int*   am   = (const int*)d_in[1];
  const float* qkvw = (const float*)d_in[2];
  const float* qkvb = (const float*)d_in[3];
  const float* qw   = (const float*)d_in[4];
  const float* qb   = (const float*)d_in[5];
  const float* kw   = (const float*)d_in[6];
  const float* kb   = (const float*)d_in[7];
  const float* vw   = (const float*)d_in[8];
  const float* vb   = (const float*)d_in[9];
  const float* ow   = (const float*)d_in[10];
  const float* ob   = (const float*)d_in[11];

  char* p = (char*)d_ws;
  auto take = [&](size_t n) { char* r = p; p += (n + 255) & ~(size_t)255; return r; };
  u16* xb    = (u16*)take(8192ull * 1024 * 2);        // also reused as attention output
  u16* qkvwT = (u16*)take(1024ull * 3072 * 2);
  u16* wb4   = (u16*)take(4ull * 1048576 * 2);        // qwb,kwb,vwb,owb
  u16* comb3 = (u16*)take(3ull * 1048576 * 2);        // comb_q (pre-scaled), comb_k, comb_v
  float* cb3 = (float*)take(3ull * 1024 * 4);
  u16* QK2   = (u16*)take(8192ull * 2048 * 2);        // fused [Q|K] (8192 x 2048)
  u16* V2t   = (u16*)take(8192ull * 1024 * 2);
  u64* pm    = (u64*)take(2048ull * 32 * 8);
  u16* Obuf  = xb;                                    // alias: xb dead after projections

  // fused prep (x->bf16, weights->bf16, qkv_w^T, combined bias, mask pack)
  prep<<<18176, 256, 0, stream>>>(x, xb, qw, kw, vw, ow, wb4, qkvw, qkvwT,
                                  qkvb, qb, kb, vb, cb3, am, pm);
  // combined weights: comb_z[o][i] = sum_m W_z[o][m] * qkv_w[z*1024+m][i]; z==0 scaled
  gemm_nt<u16, false><<<dim3(64, 1, 3), 256, 0, stream>>>(
      wb4, 1024, 1048576, qkvwT, 3072, 1024, comb3, 1024, 1048576, nullptr, 0, 8, 1024, kQScale);
  // fused Q|K projection: 256^2 8-phase, 256 balanced blocks (1/CU)
  gemm_qk8<<<256, 512, 0, stream>>>(xb, comb3, cb3, QK2);
  // V transposed: V2t[o][t] = comb_v[o]·x[t] + cb_v[o]  (bias per row)
  gemm_nt<u16, true><<<dim3(512, 1, 1), 256, 0, stream>>>(
      comb3 + 2 * 1048576, 1024, 0, xb, 1024, 0, V2t, 8192, 0, cb3 + 2048, 0, 64, 1024, 1.f);
  attn_fwd<<<512, 256, 0, stream>>>(QK2, QK2 + 1024, 2048, V2t, pm, Obuf);
  // out = O @ out_w^T + out_b  (fp32 output)
  gemm_nt<float, false><<<dim3(512, 1, 1), 256, 0, stream>>>(
      Obuf, 1024, 0, wb4 + 3 * 1048576, 1024, 0, (float*)d_out, 1024, 0, ob, 0, 8, 1024, 1.f);
}

// Round 15
// 237.696 us; speedup vs baseline: 1.4752x; 1.0029x over previous
//
#include <hip/hip_runtime.h>
#include <stdint.h>

typedef unsigned short u16;
typedef unsigned int u32;
typedef unsigned long long u64;
using f32x4 = __attribute__((ext_vector_type(4))) float;
using f32x16 = __attribute__((ext_vector_type(16))) float;
using s16x8 = __attribute__((ext_vector_type(8))) short;
using u16x4 = __attribute__((ext_vector_type(4))) unsigned short;
using u32x4 = __attribute__((ext_vector_type(4))) u32;

static constexpr float kQScale = (float)(0.08838834764831845 * 1.4426950408889634);  // SCALE*log2(e)

__device__ __forceinline__ u16 f2bf(float f) {
  uint32_t u = __float_as_uint(f);
  u += 0x7fffu + ((u >> 16) & 1u);   // RNE
  return (u16)(u >> 16);
}

__device__ __forceinline__ float fexp2(float x) {
#if __has_builtin(__builtin_amdgcn_exp2f)
  return __builtin_amdgcn_exp2f(x);
#else
  return exp2f(x);
#endif
}

__device__ __forceinline__ u32 cvtpk(float lo, float hi) {
  u32 r;
  asm("v_cvt_pk_bf16_f32 %0, %1, %2" : "=v"(r) : "v"(lo), "v"(hi));
  return r;
}

// 16x16x32 bf16 MFMA (D=C tied): C/D col=lane&15, row=4*(lane>>4)+reg [m89/m91].
__device__ __forceinline__ void mfma16(f32x4& d, s16x8 a, s16x8 b) {
  asm volatile("v_mfma_f32_16x16x32_bf16 %0, %1, %2, %0" : "+v"(d) : "v"(a), "v"(b));
}
// 32x32x16 bf16 MFMA: A row=lane&31,k=8*(lane>>5)+j; B col=lane&31;
// C/D col=lane&31, row=(reg&3)+8*(reg>>2)+4*(lane>>5) [m74/m101].
__device__ __forceinline__ void mfma32(f32x16& d, s16x8 a, s16x8 b) {
  asm volatile("v_mfma_f32_32x32x16_bf16 %0, %1, %2, %0" : "+v"(d) : "v"(a), "v"(b));
}
__device__ __forceinline__ f32x16 mfma32_z(s16x8 a, s16x8 b) {
  f32x16 d;
  asm volatile("v_mfma_f32_32x32x16_bf16 %0, %1, %2, 0" : "=&v"(d) : "v"(a), "v"(b));
  return d;
}

// async global->LDS, 16B per lane; LDS dest = wave-uniform base + lane*16 (m104).
__device__ __forceinline__ void g2lds16(const void* g, void* l) {
  __builtin_amdgcn_global_load_lds(
      (__attribute__((address_space(1))) void*)(uintptr_t)g,
      (__attribute__((address_space(3))) void*)(uint32_t)(uintptr_t)l, 16, 0, 0);
}

#define BAR() asm volatile("s_barrier" ::: "memory")

// ---------------- fused prep: x->bf16 | weights->bf16 | qkv_w^T | comb bias | mask pack ----
__global__ __launch_bounds__(256) void prep(const float* __restrict__ x, u16* __restrict__ xb,
                                            const float* __restrict__ qw, const float* __restrict__ kw,
                                            const float* __restrict__ vw, const float* __restrict__ ow,
                                            u16* __restrict__ wb4,
                                            const float* __restrict__ qkvw, u16* __restrict__ qkvwT,
                                            const float* __restrict__ qkvb, const float* __restrict__ qb,
                                            const float* __restrict__ kb, const float* __restrict__ vb,
                                            float* __restrict__ cb3,
                                            const int* __restrict__ am, u64* __restrict__ pm) {
  __shared__ u16 tile[32][33];
  const int bid = blockIdx.x, tid = threadIdx.x;
  if (bid < 8192) {                       // x (8192x1024 f32) -> bf16
    int i = (bid * 256 + tid) * 4;
    f32x4 v = *(const f32x4*)(x + i);
    u16x4 o = {f2bf(v.x), f2bf(v.y), f2bf(v.z), f2bf(v.w)};
    *(u16x4*)(xb + i) = o;
  } else if (bid < 12288) {               // 4 weights (1024^2 f32) -> bf16, contiguous
    int idx = bid - 8192;
    int z = idx >> 10;
    const float* in = z == 0 ? qw : z == 1 ? kw : z == 2 ? vw : ow;
    int i = ((idx & 1023) * 256 + tid) * 4;
    f32x4 v = *(const f32x4*)(in + i);
    u16x4 o = {f2bf(v.x), f2bf(v.y), f2bf(v.z), f2bf(v.w)};
    *(u16x4*)(wb4 + (size_t)z * 1048576 + i) = o;
  } else if (bid < 15360) {               // qkv_w (3072x1024) -> qkv_wT (1024x3072) bf16
    int idx = bid - 12288;
    int bx = idx & 31, by = idx >> 5;
    int tx = tid & 31, ty = tid >> 5;
#pragma unroll
    for (int k = 0; k < 4; ++k)
      tile[ty + k * 8][tx] = f2bf(qkvw[(size_t)(by * 32 + ty + k * 8) * 1024 + bx * 32 + tx]);
    __syncthreads();
#pragma unroll
    for (int k = 0; k < 4; ++k)
      qkvwT[(size_t)(bx * 32 + ty + k * 8) * 3072 + by * 32 + tx] = tile[tx][ty + k * 8];
  } else if (bid < 16128) {               // combined bias (fp32 exact); z==0 scaled
    int idx = bid - 15360;
    int z = idx >> 8;
    const float* w = z == 0 ? qw : (z == 1 ? kw : vw);
    const float* ba = z == 0 ? qb : (z == 1 ? kb : vb);
    const float* bi = qkvb + z * 1024;
    int o = (idx & 255) * 4 + (tid >> 6);
    int lane = tid & 63;
    float s = 0.f;
    for (int m = lane; m < 1024; m += 64) s += w[o * 1024 + m] * bi[m];
#pragma unroll
    for (int d = 1; d < 64; d <<= 1) s += __shfl_xor(s, d);
    if (lane == 0) {
      float fin = s + ba[o];
      if (z == 0) fin *= kQScale;
      cb3[z * 1024 + o] = fin;
    }
  } else {                                // mask -> bit-packed KEEP rows (2048 x 32 u64)
    int row = bid - 16128;
    int wv = tid >> 6, lane = tid & 63;
#pragma unroll
    for (int i = 0; i < 8; ++i) {
      int word = wv * 8 + i;
      u64 b = __ballot(am[(size_t)row * 2048 + word * 64 + lane] == 0);
      if (lane == 0) pm[(size_t)row * 32 + word] = b;
    }
  }
}

// ---------------- NT GEMM 128^2 (m97-style) ----------------
template <typename OUT_T, bool BIAS_PER_ROW>
__global__ __launch_bounds__(256, 2) void gemm_nt(const u16* __restrict__ A, int lda, long bsA,
                                                  const u16* __restrict__ B, int ldb, long bsB,
                                                  OUT_T* __restrict__ C, int ldc, long bsC,
                                                  const float* __restrict__ bias, long bsBias,
                                                  int NtilesN, int K, float scale_z0) {
  __shared__ __align__(16) u16 As[128 * 64];
  __shared__ __align__(16) u16 Bs[128 * 64];
  const int z = blockIdx.z;
  const float sc = (z == 0) ? scale_z0 : 1.f;
  A += (size_t)z * bsA; B += (size_t)z * bsB; C += (size_t)z * bsC;
  if (bias) bias += (size_t)z * bsBias;
  const int tm = blockIdx.x / NtilesN, tn = blockIdx.x % NtilesN;
  const int tid = threadIdx.x, lane = tid & 63, w = tid >> 6;
  const int wm = w >> 1, wn = w & 1;
  const int q = lane & 15, g = lane >> 4;
  f32x4 acc[4][4] = {};

  const u16* Ab = A + (size_t)(tm * 128 + (tid >> 3)) * lda + ((tid & 7) << 3);
  const u16* Bb = B + (size_t)(tn * 128 + (tid >> 3)) * ldb + ((tid & 7) << 3);
  char* AsW = (char*)As + (w << 10);
  char* BsW = (char*)Bs + (w << 10);

  for (int k0 = 0; k0 < K; k0 += 64) {
#pragma unroll
    for (int it = 0; it < 4; ++it) {
      g2lds16(Ab + (size_t)(it * 32) * lda + k0, AsW + it * 4096);
      g2lds16(Bb + (size_t)(it * 32) * ldb + k0, BsW + it * 4096);
    }
    __syncthreads();
#pragma unroll
    for (int kk = 0; kk < 2; ++kk) {
      s16x8 af[4], bf[4];
#pragma unroll
      for (int i = 0; i < 4; ++i)
        af[i] = *(const s16x8*)((const char*)As + (wm * 64 + i * 16 + q) * 128 + kk * 64 + g * 16);
#pragma unroll
      for (int i = 0; i < 4; ++i)
        bf[i] = *(const s16x8*)((const char*)Bs + (wn * 64 + i * 16 + q) * 128 + kk * 64 + g * 16);
#pragma unroll
      for (int mf = 0; mf < 4; ++mf)
#pragma unroll
        for (int nf = 0; nf < 4; ++nf) mfma16(acc[mf][nf], af[mf], bf[nf]);
    }
    __syncthreads();
  }
  asm volatile("s_nop 7\n\ts_nop 7");
#pragma unroll
  for (int mf = 0; mf < 4; ++mf)
#pragma unroll
    for (int nf = 0; nf < 4; ++nf) {
      const int row = tm * 128 + wm * 64 + mf * 16 + g * 4;
      const int col = tn * 128 + wn * 64 + nf * 16 + q;
      float bc = (!BIAS_PER_ROW && bias) ? bias[col] : 0.f;
#pragma unroll
      for (int r = 0; r < 4; ++r) {
        float v = acc[mf][nf][r] * sc;
        if (bias) v += BIAS_PER_ROW ? bias[row + r] : bc;
        if constexpr (sizeof(OUT_T) == 2)
          C[(size_t)(row + r) * ldc + col] = (OUT_T)f2bf(v);
        else
          C[(size_t)(row + r) * ldc + col] = (OUT_T)v;
      }
    }
}

// ------- QK projection: 256^2 8-phase schedule (m201 port). 256 blocks, 8 waves, 128KB LDS.
__global__ __launch_bounds__(512, 1) void gemm_qk8(const u16* __restrict__ A,
                                                   const u16* __restrict__ B,
                                                   const float* __restrict__ bias,
                                                   u16* __restrict__ C) {
  __shared__ __align__(16) u16 Als[2][256 * 64];   // 64KB
  __shared__ __align__(16) u16 Bls[2][256 * 64];   // 64KB
  const int bid = blockIdx.x;                      // 32x8 tiles; bid&7 = tn = per-XCD B-panel
  const int tm = bid >> 3, tn = bid & 7;
  const int tid = threadIdx.x, lane = tid & 63, w = tid >> 6;
  const int wm = w >> 2, wn = w & 3;
  const int q = lane & 15, g = lane >> 4, qk7 = q & 7;
  f32x4 acc[8][4] = {};

  const int srow = tid >> 3, sch = tid & 7;
  const int gcol = (sch ^ (srow & 7)) << 3;        // pre-swizzled source (rule 21)
  const u16* Abase = A + (size_t)(tm * 256 + srow) * 1024 + gcol;
  const u16* Bbase = B + (size_t)(tn * 256 + srow) * 1024 + gcol;

  auto stage = [&](int buf, int isB, int half, int kt) {
    const u16* src = (isB ? Bbase : Abase) + (size_t)(half * 128) * 1024 + (kt << 6);
    char* d = (char*)(isB ? &Bls[buf][0] : &Als[buf][0]) + half * 16384 + (w << 10);
    g2lds16(src, d);
    g2lds16(src + (size_t)64 * 1024, d + 8192);
  };

#define VM4 asm volatile("s_waitcnt vmcnt(4)" ::: "memory")
#define NOW ((void)0)
#define PHASE(BUF, MH, NH, SBUF, SISB, SHALF, SKT, WAIT) do {                              \
    s16x8 af[4][2], bf[2][2];                                                              \
    _Pragma("unroll") for (int mf = 0; mf < 4; ++mf)                                       \
      _Pragma("unroll") for (int kk = 0; kk < 2; ++kk)                                     \
        af[mf][kk] = *(const s16x8*)((const char*)&Als[BUF][0] +                           \
            ((MH) * 128 + wm * 64 + mf * 16 + q) * 128 + ((((kk << 2) + g) ^ qk7) << 4));  \
    _Pragma("unroll") for (int nf = 0; nf < 2; ++nf)                                       \
      _Pragma("unroll") for (int kk = 0; kk < 2; ++kk)                                     \
        bf[nf][kk] = *(const s16x8*)((const char*)&Bls[BUF][0] +                           \
            ((NH) * 128 + wn * 32 + nf * 16 + q) * 128 + ((((kk << 2) + g) ^ qk7) << 4));  \
    stage(SBUF, SISB, SHALF, SKT);                                                         \
    BAR();                                                                                 \
    __builtin_amdgcn_s_setprio(1);                                                         \
    _Pragma("unroll") for (int mf = 0; mf < 4; ++mf)                                       \
      _Pragma("unroll") for (int nf = 0; nf < 2; ++nf)                                     \
        _Pragma("unroll") for (int kk = 0; kk < 2; ++kk)                                   \
          mfma16(acc[(MH) * 4 + mf][(NH) * 2 + nf], af[mf][kk], bf[nf][kk]);               \
    __builtin_amdgcn_s_setprio(0);                                                         \
    WAIT;                                                                                  \
    BAR();                                                                                 \
  } while (0)

  stage(0, 0, 0, 0); stage(0, 1, 0, 0); stage(0, 0, 1, 0); stage(0, 1, 1, 0);
  stage(1, 0, 0, 1); stage(1, 1, 0, 1);
  VM4;
  BAR();

  for (int i = 0; i < 8; ++i) {                    // 16 K-tiles, 2 per iter
    const int ktA = 2 * i + 1;
    const int kt2 = (2 * i + 2 <= 14) ? 2 * i + 2 : 14;
    const int kt3 = (2 * i + 3 <= 15) ? 2 * i + 3 : 15;
    PHASE(0, 0, 0, 1, 0, 1, ktA, NOW);
    PHASE(0, 0, 1, 1, 1, 1, ktA, NOW);
    PHASE(0, 1, 0, 0, 0, 0, kt2, NOW);
    PHASE(0, 1, 1, 0, 1, 0, kt2, VM4);
    PHASE(1, 0, 0, 0, 0, 1, kt2, NOW);
    PHASE(1, 0, 1, 0, 1, 1, kt2, NOW);
    PHASE(1, 1, 0, 1, 0, 0, kt3, NOW);
    PHASE(1, 1, 1, 1, 1, 0, kt3, VM4);
  }
#undef PHASE
#undef VM4
#undef NOW

  asm volatile("s_nop 7\n\ts_nop 7");
#pragma unroll
  for (int mh = 0; mh < 2; ++mh)
#pragma unroll
    for (int mf = 0; mf < 4; ++mf) {
      const int row = tm * 256 + mh * 128 + wm * 64 + mf * 16 + g * 4;
#pragma unroll
      for (int nh = 0; nh < 2; ++nh)
#pragma unroll
        for (int nf = 0; nf < 2; ++nf) {
          const int col = tn * 256 + nh * 128 + wn * 32 + nf * 16 + q;
          const float bc = bias[col];
#pragma unroll
          for (int r = 0; r < 4; ++r)
            C[(size_t)(row + r) * 2048 + col] = f2bf(acc[mh * 4 + mf][nh * 2 + nf][r] + bc);
        }
    }
}

// ---------------- flash attention: pipelined QK(s+1) ∥ softmax(s), in-register P ---------
// (R13-proven: 512 blocks x 4 waves, q-tile 128, KVBLK 64; zero spill at 128 VGPR.)
__global__ __launch_bounds__(256, 2) void attn_fwd(const u16* __restrict__ Qb, const u16* __restrict__ Kb,
                                                   int ldq, const u16* __restrict__ Vt,
                                                   const u64* __restrict__ pmask,
                                                   u16* __restrict__ Ob) {
  __shared__ __align__(16) char K_lds[2][16384];  // [64 kv][128 d], 16B-chunk XOR (kv&15)
  __shared__ __align__(16) char V_lds[3][16384];  // [128 d][64 kv], chunk XOR (d&7)
  const int n = blockIdx.x;
  const int slot = n >> 3;
  const int grp = (n & 7) * 4 + (slot >> 4);
  const int qt = slot & 15;
  const int h = grp & 7, b = grp >> 3;
  const int tid = threadIdx.x, w = tid >> 6, lane = tid & 63;
  const int ql = lane & 31;
  const int hi = lane >> 5;
  const int q0 = qt * 128;

  s16x8 qf[8];
  const u16* qrow = Qb + (size_t)(b * 2048 + q0 + w * 32 + ql) * ldq + h * 128 + 8 * hi;
#pragma unroll
  for (int kd = 0; kd < 8; ++kd) qf[kd] = *(const s16x8*)(qrow + 16 * kd);

  u32x4 ov = {0x3F803F80u, 0x3F803F80u, 0x3F803F80u, 0x3F803F80u};
  const s16x8 ones = __builtin_bit_cast(s16x8, ov);

  f32x16 oacc[4] = {};   // dt: O[q=crow(reg,hi)][d = dt*32+ql]
  f32x16 lacc = {};      // l[q=crow(reg,hi)] in every column

  const int ksr = tid >> 4, ksc = tid & 15;  // K staging
  const int vsr = tid >> 3, vsc = tid & 7;   // V staging
  const int sw = ql & 15;                    // K read swizzle key
  const u64* pmrow = pmask + (size_t)(q0 + w * 32 + ql) * 32;

  auto stageK = [&](int buf, int s2) {
    const int kv0 = s2 * 64;
    char* kb = K_lds[buf] + (w << 10);
#pragma unroll
    for (int it = 0; it < 4; ++it) {
      int kr = it * 16 + ksr;
      g2lds16(Kb + (size_t)(b * 2048 + kv0 + kr) * ldq + h * 128 + ((ksc ^ (kr & 15)) << 3),
              kb + it * 4096);
    }
  };
  auto stageV = [&](int buf, int s2) {
    const int kv0 = s2 * 64;
    char* vb = V_lds[buf] + (w << 10);
#pragma unroll
    for (int it = 0; it < 4; ++it) {
      int vr = it * 32 + vsr;
      g2lds16(Vt + (size_t)(h * 128 + vr) * 8192 + b * 2048 + kv0 + ((vsc ^ (vr & 7)) << 3),
              vb + it * 4096);
    }
  };
  auto qk = [&](f32x16& d0, f32x16& d1, int kbuf) {
    const char* Kc = K_lds[kbuf];
#pragma unroll
    for (int kd = 0; kd < 8; ++kd) {
      int c = (2 * kd + hi) ^ sw;
      s16x8 kf0 = *(const s16x8*)(Kc + ql * 256 + (c << 4));
      s16x8 kf1 = *(const s16x8*)(Kc + (32 + ql) * 256 + (c << 4));
      if (kd == 0) { d0 = mfma32_z(kf0, qf[0]); d1 = mfma32_z(kf1, qf[0]); }
      else         { mfma32(d0, kf0, qf[kd]);   mfma32(d1, kf1, qf[kd]); }
    }
  };

  auto body = [&](f32x16& c0, f32x16& c1, f32x16& n0, f32x16& n1, int s, int vbR, int vbW) {
    u64 pw = pmrow[s];                         // KEEP bits
    const int sc2 = (s + 2 < 32) ? s + 2 : 31;
    stageK(s & 1, sc2);
    stageV(vbW, sc2);
    if (s + 1 < 32) qk(n0, n1, (s + 1) & 1);
    const char* Vc = V_lds[vbR];
    s16x8 pa[2];
#pragma unroll
    for (int half = 0; half < 2; ++half) {
      u32 halfm = (u32)(pw >> (32 * half + 4 * hi));
      u32 Wp[4][2];
#pragma unroll
      for (int t = 0; t < 4; ++t) {
        float e[4];
#pragma unroll
        for (int j = 0; j < 4; ++j) {
          float ev = fexp2(half == 0 ? c0[4 * t + j] : c1[4 * t + j]);
          int km;
          asm("v_bfe_i32 %0, %1, %2, 1" : "=v"(km) : "v"(halfm), "n"(8 * t + j));
          e[j] = __uint_as_float(__float_as_uint(ev) & (u32)km);
        }
        Wp[t][0] = cvtpk(e[0], e[1]);
        Wp[t][1] = cvtpk(e[2], e[3]);
      }
#pragma unroll
      for (int kq = 0; kq < 2; ++kq) {
        u32 s0 = hi ? Wp[2 * kq][0] : Wp[2 * kq + 1][0];
        u32 s1 = hi ? Wp[2 * kq][1] : Wp[2 * kq + 1][1];
        u32 r0 = (u32)__shfl_xor((int)s0, 32);
        u32 r1 = (u32)__shfl_xor((int)s1, 32);
        u32 o0 = hi ? Wp[2 * kq + 1][0] : Wp[2 * kq][0];
        u32 o1 = hi ? Wp[2 * kq + 1][1] : Wp[2 * kq][1];
        u32x4 wv;
        wv.x = hi ? r0 : o0;
        wv.y = hi ? r1 : o1;
        wv.z = hi ? o0 : r0;
        wv.w = hi ? o1 : r1;
        pa[kq] = __builtin_bit_cast(s16x8, wv);
      }
      asm volatile("s_nop 3");
      __builtin_amdgcn_s_setprio(1);
#pragma unroll
      for (int kq = 0; kq < 2; ++kq) {
        const int ks = 2 * half + kq;
#pragma unroll
        for (int dt = 0; dt < 4; ++dt) {
          int vrow = dt * 32 + ql;
          s16x8 vf = *(const s16x8*)(Vc + vrow * 128 + (((2 * ks + hi) ^ (vrow & 7)) << 4));
          mfma32(oacc[dt], pa[kq], vf);
        }
        mfma32(lacc, pa[kq], ones);
      }
      __builtin_amdgcn_s_setprio(0);
    }
    asm volatile("s_waitcnt vmcnt(4)" ::: "memory");  // own-iter 8 stages: 4 may remain in flight
    BAR();
  };

  // prologue: KV(0), KV(1); FULL drain (K(1) is read by body-0's look-ahead qk)
  stageK(0, 0); stageV(0, 0); stageK(1, 1); stageV(1, 1);
  asm volatile("s_waitcnt vmcnt(0)" ::: "memory");
  BAR();
  f32x16 sA0, sA1, sB0, sB1;
  qk(sA0, sA1, 0);
  BAR();

  int vb = 0;
  for (int s2 = 0; s2 < 16; ++s2) {
    const int s = 2 * s2;
    const int vb1 = (vb + 1 == 3) ? 0 : vb + 1;
    const int vb2 = (vb + 2 >= 3) ? vb - 1 : vb + 2;
    body(sA0, sA1, sB0, sB1, s, vb, vb2);
    body(sB0, sB1, sA0, sA1, s + 1, vb1, vb);
    vb = vb2;
  }

  asm volatile("s_nop 7\n\ts_nop 7");
#pragma unroll
  for (int dt = 0; dt < 4; ++dt)
#pragma unroll
    for (int reg = 0; reg < 16; ++reg) {
      int qr = (reg & 3) + 8 * (reg >> 2) + 4 * hi;
      size_t trow = (size_t)(b * 2048 + q0 + w * 32 + qr);
      Ob[trow * 1024 + h * 128 + dt * 32 + ql] = f2bf(oacc[dt][reg] / lacc[reg]);
    }
}

// ---------------- launcher ----------------
extern "C" void kernel_launch(void* const* d_in, const int* in_sizes, int n_in,
                              void* d_out, int out_size, void* d_ws, size_t ws_size,
                              hipStream_t stream) {
  (void)in_sizes; (void)n_in; (void)out_size; (void)ws_size;
  const float* x    = (const float*)d_in[0];
  const int*   am   = (const int*)d_in[1];
  const float* qkvw = (const float*)d_in[2];
  const float* qkvb = (const float*)d_in[3];
  const float* qw   = (const float*)d_in[4];
  const float* qb   = (const float*)d_in[5];
  const float* kw   = (const float*)d_in[6];
  const float* kb   = (const float*)d_in[7];
  const float* vw   = (const float*)d_in[8];
  const float* vb   = (const float*)d_in[9];
  const float* ow   = (const float*)d_in[10];
  const float* ob   = (const float*)d_in[11];

  char* p = (char*)d_ws;
  auto take = [&](size_t n) { char* r = p; p += (n + 255) & ~(size_t)255; return r; };
  u16* xb    = (u16*)take(8192ull * 1024 * 2);        // also reused as attention output
  u16* qkvwT = (u16*)take(1024ull * 3072 * 2);
  u16* wb4   = (u16*)take(4ull * 1048576 * 2);        // qwb,kwb,vwb,owb
  u16* comb3 = (u16*)take(3ull * 1048576 * 2);        // comb_q (pre-scaled), comb_k, comb_v
  float* cb3 = (float*)take(3ull * 1024 * 4);
  u16* QK2   = (u16*)take(8192ull * 2048 * 2);        // fused [Q|K] (8192 x 2048)
  u16* V2t   = (u16*)take(8192ull * 1024 * 2);
  u64* pm    = (u64*)take(2048ull * 32 * 8);
  u16* Obuf  = xb;                                    // alias: xb dead after projections

  // fused prep (x->bf16, weights->bf16, qkv_w^T, combined bias, mask pack)
  prep<<<18176, 256, 0, stream>>>(x, xb, qw, kw, vw, ow, wb4, qkvw, qkvwT,
                                  qkvb, qb, kb, vb, cb3, am, pm);
  // combined weights: comb_z[o][i] = sum_m W_z[o][m] * qkv_w[z*1024+m][i]; z==0 scaled
  gemm_nt<u16, false><<<dim3(64, 1, 3), 256, 0, stream>>>(
      wb4, 1024, 1048576, qkvwT, 3072, 1024, comb3, 1024, 1048576, nullptr, 0, 8, 1024, kQScale);
  // fused Q|K projection: 256^2 8-phase, 256 balanced blocks (1/CU)
  gemm_qk8<<<256, 512, 0, stream>>>(xb, comb3, cb3, QK2);
  // V transposed: V2t[o][t] = comb_v[o]·x[t] + cb_v[o]  (bias per row)
  gemm_nt<u16, true><<<dim3(512, 1, 1), 256, 0, stream>>>(
      comb3 + 2 * 1048576, 1024, 0, xb, 1024, 0, V2t, 8192, 0, cb3 + 2048, 0, 64, 1024, 1.f);
  attn_fwd<<<512, 256, 0, stream>>>(QK2, QK2 + 1024, 2048, V2t, pm, Obuf);
  // out = O @ out_w^T + out_b  (fp32 output)
  gemm_nt<float, false><<<dim3(512, 1, 1), 256, 0, stream>>>(
      Obuf, 1024, 0, wb4 + 3 * 1048576, 1024, 0, (float*)d_out, 1024, 0, ob, 0, 8, 1024, 1.f);
}